// Round 13
// baseline (643.719 us; speedup 1.0000x reference)
//
#include <hip/hip_runtime.h>

// ---------------- types / helpers ----------------
using u16 = unsigned short;
using u32 = unsigned int;
typedef __bf16 bf16x8 __attribute__((ext_vector_type(8)));
typedef u16    u16x8  __attribute__((ext_vector_type(8)));
typedef float  f32x4  __attribute__((ext_vector_type(4)));
typedef float  f32x2  __attribute__((ext_vector_type(2)));
typedef u32    u32x4  __attribute__((ext_vector_type(4)));
typedef u32    u32x2  __attribute__((ext_vector_type(2)));

__device__ __forceinline__ float bf2f(u16 h){ u32 u = ((u32)h)<<16; float f; __builtin_memcpy(&f,&u,4); return f; }
__device__ __forceinline__ u16 f2bf(float f){ u32 u; __builtin_memcpy(&u,&f,4); u32 r = (u + 0x7FFFu + ((u>>16)&1u))>>16; return (u16)r; }
__device__ __forceinline__ float bflo(u32 w){ return bf2f((u16)(w & 0xFFFFu)); }
__device__ __forceinline__ float bfhiw(u32 w){ return bf2f((u16)(w >> 16)); }
__device__ __forceinline__ float sigx(float x){ float e = __expf(-fabsf(x)); float p = 1.f/(1.f+e); return (x>=0.f) ? p : 1.f-p; }

// lgkm-only barrier: LDS visibility without draining in-flight global prefetches.
#define BAR_LGKM() asm volatile("s_waitcnt lgkmcnt(0)\n\ts_barrier" ::: "memory")

// dtype-dual loads from EXTERNAL buffers (f32 or bf16)
__device__ __forceinline__ float ldsc(const void* p, size_t i, bool f32){
  return f32 ? ((const float*)p)[i] : bf2f(((const u16*)p)[i]);
}
__device__ __forceinline__ u32x4 ld8bf(const void* p, size_t i, bool f32){
  if (!f32) return *(const u32x4*)((const u16*)p + i);
  const f32x4* q = (const f32x4*)((const float*)p + i);
  f32x4 a = q[0], b = q[1];
  u32x4 r;
  r.x = (u32)f2bf(a.x) | ((u32)f2bf(a.y)<<16);
  r.y = (u32)f2bf(a.z) | ((u32)f2bf(a.w)<<16);
  r.z = (u32)f2bf(b.x) | ((u32)f2bf(b.y)<<16);
  r.w = (u32)f2bf(b.z) | ((u32)f2bf(b.w)<<16);
  return r;
}
__device__ __forceinline__ void unpack8(u32x4 v, float* f){
  f[0]=bflo(v.x); f[1]=bfhiw(v.x); f[2]=bflo(v.y); f[3]=bfhiw(v.y);
  f[4]=bflo(v.z); f[5]=bfhiw(v.z); f[6]=bflo(v.w); f[7]=bfhiw(v.w);
}

// B=2, L=4096, DM=1024, H=8, HQK=96, HV=192, KEY=768, VAL=1536, CHUNK=64, NCH=64

// ---------------- runtime dtype probe ----------------
__global__ void detect_kernel(const u16* __restrict__ probe, int* __restrict__ flag){
  int t = threadIdx.x;
  int bad = 0;
  for (int i=t; i<1024; i+=64){
    u16 h = probe[i];
    int e = (h>>7)&0xFF;
    if (e >= 0xC0) bad = 1;
  }
  unsigned long long anyb = __ballot(bad);
  if (t==0) *flag = (anyb != 0ull) ? 1 : 0;
}

// ---------------- fused weight transposes (5 regions) + u->bf16 copy (one dispatch) ----------------
__global__ void transpose5(const void* __restrict__ Wq, const void* __restrict__ Wk,
                           const void* __restrict__ Wv, const void* __restrict__ Wg,
                           const void* __restrict__ Wo, const void* __restrict__ U,
                           u16* __restrict__ WqT, u16* __restrict__ WkT, u16* __restrict__ WvT,
                           u16* __restrict__ WgT, u16* __restrict__ WoT, u16* __restrict__ ubf,
                           const int* __restrict__ flagp){
  const bool f32 = (*flagp != 0);
  const int bid = blockIdx.x;
  const int t = threadIdx.x;
  if (bid >= 6144){
    size_t base = ((size_t)(bid-6144)*256 + t) * 16;
    u32x4 a = ld8bf(U, base, f32);
    u32x4 b = ld8bf(U, base+8, f32);
    *(u32x4*)(ubf + base)     = a;
    *(u32x4*)(ubf + base + 8) = b;
    return;
  }
  const void* in; u16* out; int C; int local;
  int R;
  if (bid < 768){ in=Wq; out=WqT; R=1024; C=768;  local=bid; }
  else if (bid < 1536){ in=Wk; out=WkT; R=1024; C=768;  local=bid-768; }
  else if (bid < 3072){ in=Wv; out=WvT; R=1024; C=1536; local=bid-1536; }
  else if (bid < 4608){ in=Wg; out=WgT; R=1024; C=1536; local=bid-3072; }
  else { in=Wo; out=WoT; R=1536; C=1024; local=bid-4608; }
  const int nCx = C>>5;
  const int c0 = (local % nCx)*32, r0 = (local / nCx)*32;
  __shared__ u16 tile[32][33];
  int tx = t & 31, ty = t >> 5;
  #pragma unroll
  for (int j=0;j<4;j++){
    int r = r0 + ty + j*8;
    size_t g = (size_t)r*C + c0 + tx;
    tile[ty+j*8][tx] = f32 ? f2bf(((const float*)in)[g]) : ((const u16*)in)[g];
  }
  __syncthreads();
  #pragma unroll
  for (int j=0;j<4;j++){ int c = c0 + ty + j*8; out[(size_t)c*R + r0 + tx] = tile[tx][ty+j*8]; }
}

// ---------------- bf16 MFMA GEMM (final Wo GEMM), 1D grid + XCD swizzle ----------------
__global__ __launch_bounds__(256,2) void gemm_bt(const void* __restrict__ A, const u16* __restrict__ Bt,
                                                 void* __restrict__ C, int M, int N, int K,
                                                 const int* __restrict__ flagp, int a_ext, int c_ext,
                                                 int sanitize){
  __shared__ __align__(16) u16 As[128*32];
  __shared__ __align__(16) u16 Bs[128*32];
  const int fl = *flagp;
  const bool af32 = a_ext && fl;
  const bool cf32 = c_ext && fl;
  const int t = threadIdx.x;
  const int bid = blockIdx.x;
  const int nbn = N>>7, rpx = (M>>7)>>3;
  const int x2 = bid & 7, s = bid >> 3;
  const int bm = (x2*rpx + s/nbn)*128;
  const int bn = (s % nbn)*128;
  const int wave = t>>6, lane = t&63, quad = lane>>4, l16 = lane&15;
  const int wm = (wave>>1)*64, wn = (wave&1)*64;
  f32x4 acc[4][4] = {};
  const int row0 = t>>2, kp = (t&3)*8;
  const size_t iA0 = (size_t)(bm+row0)*K + kp;
  const size_t iA1 = iA0 + (size_t)64*K;
  const u16* pB0 = Bt + (size_t)(bn+row0)*K + kp;
  const u16* pB1 = pB0 + (size_t)64*K;
  u32x4 ra0 = ld8bf(A, iA0, af32);
  u32x4 ra1 = ld8bf(A, iA1, af32);
  u32x4 rb0 = *(const u32x4*)pB0;
  u32x4 rb1 = *(const u32x4*)pB1;
  const int nk = K>>5;
  for (int kt=0; kt<nk; ++kt){
    __syncthreads();
    ((u32x4*)As)[t]     = ra0;
    ((u32x4*)As)[t+256] = ra1;
    ((u32x4*)Bs)[t]     = rb0;
    ((u32x4*)Bs)[t+256] = rb1;
    __syncthreads();
    if (kt+1 < nk){
      int o = (kt+1)*32;
      ra0 = ld8bf(A, iA0 + o, af32); ra1 = ld8bf(A, iA1 + o, af32);
      rb0 = *(const u32x4*)(pB0 + o); rb1 = *(const u32x4*)(pB1 + o);
    }
    bf16x8 af[4], bfv[4];
    #pragma unroll
    for (int i=0;i<4;i++){
      af[i]  = *(const bf16x8*)&As[(wm + i*16 + l16)*32 + quad*8];
      bfv[i] = *(const bf16x8*)&Bs[(wn + i*16 + l16)*32 + quad*8];
    }
    #pragma unroll
    for (int i=0;i<4;i++)
      #pragma unroll
      for (int j=0;j<4;j++)
        acc[i][j] = __builtin_amdgcn_mfma_f32_16x16x32_bf16(af[i], bfv[j], acc[i][j], 0,0,0);
  }
  #pragma unroll
  for (int i=0;i<4;i++)
    #pragma unroll
    for (int j=0;j<4;j++)
      #pragma unroll
      for (int r2=0;r2<4;r2++){
        int m = bm + wm + i*16 + quad*4 + r2;
        int n = bn + wn + j*16 + l16;
        float v = acc[i][j][r2];
        if (sanitize && !(v==v && v<1e30f && v>-1e30f)) v = 0.f;
        if (cf32) ((float*)C)[(size_t)m*N + n] = v;
        else      ((u16*)C)[(size_t)m*N + n] = f2bf(v);
      }
}

// ---------------- q/k/v projection GEMMs, pure (round-9 mapping, bid%8 XCD swizzle) ----------------
// gkbeta moved to prep v4 (rounds 9-12 showed every placement inside this dispatch loses:
// tail-latency when sequential, L2 weight-eviction when interleaved).
__global__ __launch_bounds__(256,2) void gemm_qkv(const u16* __restrict__ A,
                                                  const u16* __restrict__ BtQ, const u16* __restrict__ BtK,
                                                  const u16* __restrict__ BtV,
                                                  u16* __restrict__ Cq, u16* __restrict__ Ck, u16* __restrict__ Cv){
  __shared__ __align__(16) u16 As[128*32];
  __shared__ __align__(16) u16 Bs[128*32];
  const int t = threadIdx.x;
  const int bid = blockIdx.x;                 // 0..1535
  const int x2 = bid & 7, s = bid >> 3;       // s 0..191
  const int bm = (x2*8 + s/24)*128;
  const int cgrp = s % 24;
  const u16* Bt; u16* C; int N, bn;
  if (cgrp < 6){ Bt=BtQ; C=Cq; N=768; bn=cgrp*128; }
  else if (cgrp < 12){ Bt=BtK; C=Ck; N=768; bn=(cgrp-6)*128; }
  else { Bt=BtV; C=Cv; N=1536; bn=(cgrp-12)*128; }
  const int K = 1024;
  const int wave = t>>6, lane = t&63, quad = lane>>4, l16 = lane&15;
  const int wm = (wave>>1)*64, wn = (wave&1)*64;
  f32x4 acc[4][4] = {};
  const int row0 = t>>2, kp = (t&3)*8;
  const u16* pA0 = A + (size_t)(bm+row0)*K + kp;
  const u16* pA1 = pA0 + (size_t)64*K;
  const u16* pB0 = Bt + (size_t)(bn+row0)*K + kp;
  const u16* pB1 = pB0 + (size_t)64*K;
  u32x4 ra0 = *(const u32x4*)pA0;
  u32x4 ra1 = *(const u32x4*)pA1;
  u32x4 rb0 = *(const u32x4*)pB0;
  u32x4 rb1 = *(const u32x4*)pB1;
  for (int kt=0; kt<32; ++kt){
    __syncthreads();
    ((u32x4*)As)[t]     = ra0;
    ((u32x4*)As)[t+256] = ra1;
    ((u32x4*)Bs)[t]     = rb0;
    ((u32x4*)Bs)[t+256] = rb1;
    __syncthreads();
    if (kt+1 < 32){
      int o = (kt+1)*32;
      ra0 = *(const u32x4*)(pA0 + o); ra1 = *(const u32x4*)(pA1 + o);
      rb0 = *(const u32x4*)(pB0 + o); rb1 = *(const u32x4*)(pB1 + o);
    }
    bf16x8 af[4], bfv[4];
    #pragma unroll
    for (int i=0;i<4;i++){
      af[i]  = *(const bf16x8*)&As[(wm + i*16 + l16)*32 + quad*8];
      bfv[i] = *(const bf16x8*)&Bs[(wn + i*16 + l16)*32 + quad*8];
    }
    #pragma unroll
    for (int i=0;i<4;i++)
      #pragma unroll
      for (int j=0;j<4;j++)
        acc[i][j] = __builtin_amdgcn_mfma_f32_16x16x32_bf16(af[i], bfv[j], acc[i][j], 0,0,0);
  }
  #pragma unroll
  for (int i=0;i<4;i++)
    #pragma unroll
    for (int j=0;j<4;j++)
      #pragma unroll
      for (int r2=0;r2<4;r2++){
        int m = bm + wm + i*16 + quad*4 + r2;
        int n = bn + wn + j*16 + l16;
        C[(size_t)m*N + n] = f2bf(acc[i][j][r2]);
      }
}

// ---------------- prep v4: gkbeta (f32 fast path) + role-split vectorized convs ----------------
// gkbeta returns home: 8192 co-dense blocks keep the 64KB Wgk/Wb set L2-hot (round 7/8 showed
// FETCH ~115MB total with this structure), and the f32 fast path (verified rounds 9-12,
// bit-identical values) removes the f32->bf16->f32 round-trip that made round-8's version
// VALU-bound. Reduction tree and accumulation order identical to rounds 9-12.
__global__ __launch_bounds__(384) void prep_kernel(
    const void* __restrict__ u, const void* __restrict__ Wgk, const void* __restrict__ Wb,
    const void* __restrict__ b_b, const void* __restrict__ A_log, const void* __restrict__ dt_b,
    const u16* __restrict__ qraw, const u16* __restrict__ kraw, const u16* __restrict__ vraw,
    const void* __restrict__ cq, const void* __restrict__ ck, const void* __restrict__ cv,
    float* __restrict__ gk, float* __restrict__ beta,
    u16* __restrict__ qn, u16* __restrict__ kn, u16* __restrict__ vb,
    const int* __restrict__ flagp){
  const bool f32 = (*flagp != 0);
  const int bl = blockIdx.x;
  const int b = bl>>12, l = bl&4095;
  const int t = threadIdx.x;
  __shared__ float red[4][16];
  __shared__ float sqP[96], skP[96];
  __shared__ float nrmq[8], nrmk[8];
  __shared__ float bS2[8];

  // ---- phase 0: gk/beta on threads 0..255 (f32 fast path; order identical to r9-r12) ----
  if (t < 256){
    float accg[8] = {0,0,0,0,0,0,0,0};
    float accb[8] = {0,0,0,0,0,0,0,0};
    if (f32){
      const float* uf  = (const float*)u + (size_t)bl*1024;
      const float* wgf = (const float*)Wgk;
      const float* wbf = (const float*)Wb;
      for (int d=t; d<1024; d+=256){
        float uv = uf[d];
        f32x4 ga = *(const f32x4*)(wgf + (size_t)d*8);
        f32x4 gb = *(const f32x4*)(wgf + (size_t)d*8 + 4);
        f32x4 ba = *(const f32x4*)(wbf + (size_t)d*8);
        f32x4 bb = *(const f32x4*)(wbf + (size_t)d*8 + 4);
        accg[0] += uv*ga.x; accg[1] += uv*ga.y; accg[2] += uv*ga.z; accg[3] += uv*ga.w;
        accg[4] += uv*gb.x; accg[5] += uv*gb.y; accg[6] += uv*gb.z; accg[7] += uv*gb.w;
        accb[0] += uv*ba.x; accb[1] += uv*ba.y; accb[2] += uv*ba.z; accb[3] += uv*ba.w;
        accb[4] += uv*bb.x; accb[5] += uv*bb.y; accb[6] += uv*bb.z; accb[7] += uv*bb.w;
      }
    } else {
      const u16* uh = (const u16*)u + (size_t)bl*1024;
      for (int d=t; d<1024; d+=256){
        float uv = bf2f(uh[d]);
        u32x4 wg = *(const u32x4*)((const u16*)Wgk + (size_t)d*8);
        u32x4 wb = *(const u32x4*)((const u16*)Wb  + (size_t)d*8);
        accg[0] += uv*bflo(wg.x); accg[1] += uv*bfhiw(wg.x);
        accg[2] += uv*bflo(wg.y); accg[3] += uv*bfhiw(wg.y);
        accg[4] += uv*bflo(wg.z); accg[5] += uv*bfhiw(wg.z);
        accg[6] += uv*bflo(wg.w); accg[7] += uv*bfhiw(wg.w);
        accb[0] += uv*bflo(wb.x); accb[1] += uv*bfhiw(wb.x);
        accb[2] += uv*bflo(wb.y); accb[3] += uv*bfhiw(wb.y);
        accb[4] += uv*bflo(wb.z); accb[5] += uv*bfhiw(wb.z);
        accb[6] += uv*bflo(wb.w); accb[7] += uv*bfhiw(wb.w);
      }
    }
    #pragma unroll
    for (int h=0;h<8;h++){
      #pragma unroll
      for (int off=32; off>=1; off>>=1){
        accg[h] += __shfl_down(accg[h], off);
        accb[h] += __shfl_down(accb[h], off);
      }
    }
    int wv = t>>6, lane = t&63;
    if (lane==0){
      #pragma unroll
      for (int h=0;h<8;h++){ red[wv][h]=accg[h]; red[wv][8+h]=accb[h]; }
    }
  }
  __syncthreads();
  if (t<16){
    float sum = red[0][t]+red[1][t]+red[2][t]+red[3][t];
    if (t<8){
      int h=t;
      float x = sum + ldsc(dt_b, h, f32);
      float sp = (x>20.f) ? x : log1pf(__expf(x));
      gk[(size_t)(b*8+h)*4096 + l] = -__expf(ldsc(A_log, h, f32)) * sp;
    } else {
      int h=t-8;
      float x = sum + ldsc(b_b, h, f32);
      float bv = sigx(x);
      beta[(size_t)(b*8+h)*4096 + l] = bv;
      bS2[h] = bv;
    }
  }
  __syncthreads();

  // ---- role-split vectorized convs (v3 structure, bS2 from LDS) ----
  const int base = b*4096;
  int role, c0;
  if (t < 96){ role=0; c0=t*8; }
  else if (t < 192){ role=1; c0=(t-96)*8; }
  else { role=2; c0=(t-192)*8; }
  const u16* raw = (role==0)? qraw : (role==1)? kraw : vraw;
  const void* cw = (role==0)? cq : (role==1)? ck : cv;
  const int C = (role==2)? 1536 : 768;

  float w[8][4];
  #pragma unroll
  for (int g=0; g<4; g++){
    u32x4 W = ld8bf(cw, (size_t)c0*4 + g*8, f32);
    w[g*2+0][0]=bflo(W.x); w[g*2+0][1]=bfhiw(W.x); w[g*2+0][2]=bflo(W.y); w[g*2+0][3]=bfhiw(W.y);
    w[g*2+1][0]=bflo(W.z); w[g*2+1][1]=bfhiw(W.z); w[g*2+1][2]=bflo(W.w); w[g*2+1][3]=bfhiw(W.w);
  }
  float acc[8];
  #pragma unroll
  for (int ch=0; ch<8; ch++) acc[ch] = 0.f;
  #pragma unroll
  for (int j=0;j<4;j++){
    if (l >= 3-j){
      u32x4 iv = *(const u32x4*)(raw + (size_t)(base+l-3+j)*C + c0);
      float in[8]; unpack8(iv, in);
      #pragma unroll
      for (int ch=0;ch<8;ch++) acc[ch] += in[ch]*w[ch][j];
    }
  }
  #pragma unroll
  for (int ch=0;ch<8;ch++) acc[ch] = acc[ch]*sigx(acc[ch]);

  if (role==2){
    int h = c0/192, d0 = c0 - h*192;
    float bv = bS2[h];
    u32x4 pv;
    pv.x = (u32)f2bf(acc[0]*bv) | ((u32)f2bf(acc[1]*bv)<<16);
    pv.y = (u32)f2bf(acc[2]*bv) | ((u32)f2bf(acc[3]*bv)<<16);
    pv.z = (u32)f2bf(acc[4]*bv) | ((u32)f2bf(acc[5]*bv)<<16);
    pv.w = (u32)f2bf(acc[6]*bv) | ((u32)f2bf(acc[7]*bv)<<16);
    *(u32x4*)&vb[((size_t)(b*8+h)*4096 + l)*192 + d0] = pv;
  } else {
    float ss = 0.f;
    #pragma unroll
    for (int ch=0;ch<8;ch++) ss += acc[ch]*acc[ch];
    if (role==0) sqP[t] = ss; else skP[t-96] = ss;
  }
  __syncthreads();
  if (t < 8){
    float s = 0.f;
    #pragma unroll
    for (int j=0;j<12;j++) s += sqP[t*12+j];
    nrmq[t] = fmaxf(sqrtf(s), 1e-12f);
  } else if (t < 16){
    int h = t-8;
    float s = 0.f;
    #pragma unroll
    for (int j=0;j<12;j++) s += skP[h*12+j];
    nrmk[h] = fmaxf(sqrtf(s), 1e-12f);
  }
  __syncthreads();
  if (role==0){
    int h = c0/96, d0 = c0 - h*96;
    float nr = nrmq[h];
    u32x4 pv;
    pv.x = (u32)f2bf(acc[0]/nr*0.10206207261596575f) | ((u32)f2bf(acc[1]/nr*0.10206207261596575f)<<16);
    pv.y = (u32)f2bf(acc[2]/nr*0.10206207261596575f) | ((u32)f2bf(acc[3]/nr*0.10206207261596575f)<<16);
    pv.z = (u32)f2bf(acc[4]/nr*0.10206207261596575f) | ((u32)f2bf(acc[5]/nr*0.10206207261596575f)<<16);
    pv.w = (u32)f2bf(acc[6]/nr*0.10206207261596575f) | ((u32)f2bf(acc[7]/nr*0.10206207261596575f)<<16);
    *(u32x4*)&qn[((size_t)(b*8+h)*4096 + l)*96 + d0] = pv;
  } else if (role==1){
    int h = c0/96, d0 = c0 - h*96;
    float nr = nrmk[h];
    u32x4 pv;
    pv.x = (u32)f2bf(acc[0]/nr*1.0f) | ((u32)f2bf(acc[1]/nr*1.0f)<<16);
    pv.y = (u32)f2bf(acc[2]/nr*1.0f) | ((u32)f2bf(acc[3]/nr*1.0f)<<16);
    pv.z = (u32)f2bf(acc[4]/nr*1.0f) | ((u32)f2bf(acc[5]/nr*1.0f)<<16);
    pv.w = (u32)f2bf(acc[6]/nr*1.0f) | ((u32)f2bf(acc[7]/nr*1.0f)<<16);
    *(u32x4*)&kn[((size_t)(b*8+h)*4096 + l)*96 + d0] = pv;
  }
}

// ---------------- chunkprep: 320 threads, single-pass 288-col substitution + decay tables + kTw emit ----------------
__global__ __launch_bounds__(320,2) void chunkprep_kernel(
    const u16* __restrict__ qn, u16* __restrict__ knw, const u16* __restrict__ vb,
    const float* __restrict__ beta, const float* __restrict__ gk,
    u16* __restrict__ attn, u16* __restrict__ kcd, u16* __restrict__ uA,
    float* __restrict__ edG, float* __restrict__ aG){
  __shared__ __align__(16) u16 kS[64*104];
  __shared__ __align__(16) u16 qS[64*104];
  __shared__ float M1[64*64];
  __shared__ float M2[64*64];
  __shared__ float bS[64], dS[64], wS2[64];
  const int t = threadIdx.x;
  const int bhn = blockIdx.x;
  const size_t rowb = (size_t)bhn*64;
  const int w = t>>6, l = t&63, l16 = l&15, quad = l>>4;

  #pragma unroll
  for (int j=0;j<3;j++){
    int v = t + 320*j;
    if (v < 768){
      int rr = v/12, c8 = v - rr*12;
      size_t g = (rowb+rr)*96 + c8*8;
      *(u32x4*)&kS[rr*104 + c8*8] = *(const u32x4*)(knw + g);
      *(u32x4*)&qS[rr*104 + c8*8] = *(const u32x4*)(qn + g);
    }
  }
  if (t<64){
    bS[t] = beta[rowb+t];
    float g = gk[rowb+t];
    #pragma unroll
    for (int off=1; off<64; off<<=1){
      float xx = __shfl_up(g, off);
      if (t >= off) g += xx;
    }
    dS[t] = g;
    float dl = __shfl(g, 63);
    edG[rowb+t] = __expf(g);
    wS2[t] = __expf(dl - g);
    if (t==0) aG[bhn] = __expf(dl);
  }
  __syncthreads();   // kS staged (kn reads complete), wS2 ready -> safe to overwrite kn with kTw

  for (int idx=t; idx<6144; idx+=320){
    int d = idx>>6, ll = idx&63;
    knw[(size_t)bhn*6144 + idx] = f2bf(bf2f(kS[ll*104 + d])*wS2[ll]);
  }

  float x[64];
  const int mode0 = (t<192) ? 0 : 1;
  const int c0 = (t<192) ? t : (t-192);
  const bool active = (t < 288);
  if (active){
    if (mode0==0){
      #pragma unroll
      for (int i=0;i<64;i++) x[i] = bf2f(vb[(rowb+i)*192 + c0]);
    } else {
      #pragma unroll
      for (int i=0;i<64;i++) x[i] = bS[i]*bf2f(kS[i*104 + c0]);
    }
  }

  if (t < 256){
    bf16x8 qA[3], kA[3];
    #pragma unroll
    for (int ks=0;ks<3;ks++){
      qA[ks] = *(const bf16x8*)&qS[(w*16+l16)*104 + ks*32 + quad*8];
      kA[ks] = *(const bf16x8*)&kS[(w*16+l16)*104 + ks*32 + quad*8];
    }
    const size_t ab = (size_t)bhn*4096;
    #pragma unroll
    for (int nt=0;nt<4;nt++){
      f32x4 aQ = {0.f,0.f,0.f,0.f}, aK = {0.f,0.f,0.f,0.f};
      #pragma unroll
      for (int ks=0;ks<3;ks++){
        bf16x8 Bf = *(const bf16x8*)&kS[(nt*16+l16)*104 + ks*32 + quad*8];
        aQ = __builtin_amdgcn_mfma_f32_16x16x32_bf16(qA[ks], Bf, aQ,0,0,0);
        aK = __builtin_amdgcn_mfma_f32_16x16x32_bf16(kA[ks], Bf, aK,0,0,0);
      }
      #pragma unroll
      for (int r=0;r<4;r++){
        int row = w*16 + quad*4 + r;
        int col = nt*16 + l16;
        float lm = __expf(fminf(dS[row]-dS[col], 0.f));
        attn[ab + row*64 + col] = (col<=row) ? f2bf(aQ[r]*lm) : (u16)0;
        if (col<row){
          float kkb = aK[r]*bS[row];
          M2[row*64+col] = kkb;
          M1[row*64+col] = kkb*lm;
        }
      }
    }
  }
  __syncthreads();

  if (active){
    const float* Mb = (mode0==0) ? M1 : M2;
    #pragma unroll
    for (int i=1;i<64;i++){
      float acc = x[i];
      #pragma unroll
      for (int m=0;m<i;m++) acc -= Mb[i*64+m]*x[m];
      x[i] = acc;
    }
    if (mode0==0){
      #pragma unroll
      for (int i=0;i<64;i++) uA[(rowb+i)*192 + c0] = f2bf(x[i]);
    } else {
      #pragma unroll
      for (int i=0;i<64;i++) kcd[(rowb+i)*96 + c0] = f2bf(x[i]);
    }
  }
}

// ---------------- fused: scan (blocks 0..191) + glin GEMM (blocks 192..959) ----------------
__global__ __launch_bounds__(256,1) void scan_glin_kernel(
    const u16* __restrict__ qn, const u16* __restrict__ kTw, const u16* __restrict__ kcd,
    const u16* __restrict__ attn, const u16* __restrict__ uA,
    const float* __restrict__ edG, const float* __restrict__ aG,
    u16* __restrict__ o,
    const u16* __restrict__ Ag, const u16* __restrict__ Btg,
    u16* __restrict__ Cg0, u16* __restrict__ Cg1, u16* __restrict__ Cg2, u16* __restrict__ Cg3){
  __shared__ __align__(16) char smem[16640];
  const int bid = blockIdx.x;
  const int t = threadIdx.x;

  if (bid >= 192){
    // ---- glin GEMM tile, XCD-swizzled, bf16 A ----
    u16* As = (u16*)smem;
    u16* Bs = (u16*)(smem + 8192);
    const int j = bid - 192;                 // 0..767
    const int x2 = j & 7, s = j >> 3;        // s 0..95
    const int bm = (x2*8 + s/12)*128;
    const int bn = (s % 12)*128;
    const int wave = t>>6, lane = t&63, quad = lane>>4, l16 = lane&15;
    const int wm = (wave>>1)*64, wn = (wave&1)*64;
    f32x4 acc[4][4] = {};
    const int row0 = t>>2, kp = (t&3)*8;
    const u16* pA0 = Ag + (size_t)(bm+row0)*1024 + kp;
    const u16* pA1 = pA0 + (size_t)64*1024;
    const u16* pB0 = Btg + (size_t)(bn+row0)*1024 + kp;
    const u16* pB1 = pB0 + (size_t)64*1024;
    u32x4 ra0 = *(const u32x4*)pA0;
    u32x4 ra1 = *(const u32x4*)pA1;
    u32x4 rb0 = *(const u32x4*)pB0;
    u32x4 rb1 = *(const u32x4*)pB1;
    for (int kt=0; kt<32; ++kt){
      __syncthreads();
      ((u32x4*)As)[t]     = ra0;
      ((u32x4*)As)[t+256] = ra1;
      ((u32x4*)Bs)[t]     = rb0;
      ((u32x4*)Bs)[t+256] = rb1;
      __syncthreads();
      if (kt+1 < 32){
        int o2 = (kt+1)*32;
        ra0 = *(const u32x4*)(pA0 + o2); ra1 = *(const u32x4*)(pA1 + o2);
        rb0 = *(const u32x4*)(pB0 + o2); rb1 = *(const u32x4*)(pB1 + o2);
      }
      bf16x8 af[4], bfv[4];
      #pragma unroll
      for (int i=0;i<4;i++){
        af[i]  = *(const bf16x8*)&As[(wm + i*16 + l16)*32 + quad*8];
        bfv[i] = *(const bf16x8*)&Bs[(wn + i*16 + l16)*32 + quad*8];
      }
      #pragma unroll
      for (int i=0;i<4;i++)
        #pragma unroll
        for (int j2=0;j2<4;j2++)
          acc[i][j2] = __builtin_amdgcn_mfma_f32_16x16x32_bf16(af[i], bfv[j2], acc[i][j2], 0,0,0);
    }
    u16* Cp; int mo;
    if (bm < 5376){ Cp = Cg0; mo = bm; }
    else if (bm < 6656){ Cp = Cg1; mo = bm - 5376; }
    else if (bm < 7680){ Cp = Cg2; mo = bm - 6656; }
    else { Cp = Cg3; mo = bm - 7680; }
    #pragma unroll
    for (int i=0;i<4;i++)
      #pragma unroll
      for (int j2=0;j2<4;j2++)
        #pragma unroll
        for (int r2=0;r2<4;r2++){
          int m = mo + wm + i*16 + quad*4 + r2;
          int n = bn + wn + j2*16 + l16;
          Cp[(size_t)m*1536 + n] = f2bf(acc[i][j2][r2]);
        }
    return;
  }

  // ---- scan (192 blocks; bh = bid%16 so all 12 eg-blocks of a bh share one XCD) ----
  __builtin_amdgcn_s_setprio(1);   // latency-critical: outprioritize co-resident glin waves
  const int bh = bid % 16, eg = bid / 16;
  const int e0 = eg*16;
  const int w = t>>6, l = t&63, l16 = l&15, quad = l>>4;

  u16* vnewT = (u16*)smem;                 // [16*72]
  u16* Sbf   = (u16*)(smem + 2304);        // [16*104]  S^T bf16 [col][d]

  for (int i=t; i<16*104; i+=256) Sbf[i] = 0;

  size_t rowb = (size_t)bh*4096;
  size_t ab   = (size_t)bh*64*4096;

  u32x4 kcdF[3], qF[3], attF[2]; u16 uF[4];
  u32x4 kuC[2][2], kuN[2][2];              // kTw fragments: [slot][ks], current/next
  auto pfAB = [&](size_t rowbN){
    #pragma unroll
    for (int ks=0; ks<3; ks++){
      size_t gg = (rowbN + w*16 + l16)*96 + ks*32 + quad*8;
      kcdF[ks] = *(const u32x4*)(kcd + gg);
      qF[ks]   = *(const u32x4*)(qn + gg);
    }
  };
  auto pfATT = [&](size_t abN){
    #pragma unroll
    for (int ks=0; ks<2; ks++)
      attF[ks] = *(const u32x4*)(attn + abN + (w*16 + l16)*64 + ks*32 + quad*8);
  };
  auto pfU = [&](size_t rowbN){
    #pragma unroll
    for (int r=0;r<4;r++)
      uF[r] = uA[(rowbN + w*16 + quad*4 + r)*192 + e0 + l16];
  };
  auto pfKU = [&](size_t chunkIdx, u32x4 (&dst)[2][2]){
    #pragma unroll
    for (int i=0;i<2;i++){
      int tid = w + 4*i;
      if (tid < 6){
        size_t base = chunkIdx*6144 + (size_t)(tid*16 + l16)*64 + quad*8;
        dst[i][0] = *(const u32x4*)(kTw + base);
        dst[i][1] = *(const u32x4*)(kTw + base + 32);
      }
    }
  };

  // prologue
  pfAB(rowb); pfU(rowb); pfATT(ab);
  pfKU(rowb>>6, kuC);
  f32x4 edC = *(const f32x4*)&edG[rowb + w*16 + quad*4];
  float aexpC = aG[rowb>>6];
  __syncthreads();           // Sbf zeros visible
  f32x4 Sreg[2] = {};

  for (int n=0;n<64;n++){
    const size_t rowbN = rowb + 64;
    const size_t abN = ab + 4096;
    f32x4 edN = {0.f,0.f,0.f,0.f};
    float aexpN = 0.f;
    if (n<63){
      pfKU(rowbN>>6, kuN);
      edN = *(const f32x4*)&edG[rowbN + w*16 + quad*4];
      aexpN = aG[rowbN>>6];
    }
    // phase 1: accA = kcd@S, accQ = q@S
    f32x4 accA = {0.f,0.f,0.f,0.f}, accQ = {0.f,0.f,0.f,0.f};
    #pragma unroll
    for (int ks=0;ks<3;ks++){
      bf16x8 Bf = *(const bf16x8*)&Sbf[l16*104 + ks*32 + quad*8];
      accA = __builtin_amdgcn_mfma_f32_16x16x32_bf16(*(const bf16x8*)&kcdF[ks], Bf, accA,0,0,0);
      accQ = __builtin_amdgcn_mfma_f32_16x16x32_bf16(*(const bf16x8*)&qF[ks],  Bf, accQ,0,0,0);
    }
    #pragma unroll
    for (int r=0;r<4;r++){
      float vn = bf2f(uF[r]) - edC[r]*accA[r];
      vnewT[l16*72 + (w*16+quad*4+r)] = f2bf(vn);
      accQ[r] *= edC[r];
    }
    if (n<63){ pfAB(rowbN); pfU(rowbN); }
    BAR_LGKM();              // sync1: vnewT visible; global prefetches stay in flight
    // phase 2: accQ += attn @ vnew
    #pragma unroll
    for (int ks=0;ks<2;ks++){
      bf16x8 Bv = *(const bf16x8*)&vnewT[l16*72 + ks*32 + quad*8];
      accQ = __builtin_amdgcn_mfma_f32_16x16x32_bf16(*(const bf16x8*)&attF[ks], Bv, accQ,0,0,0);
    }
    #pragma unroll
    for (int r=0;r<4;r++)
      o[(rowb + w*16 + quad*4 + r)*192 + e0 + l16] = f2bf(accQ[r]);
    if (n<63) pfATT(abN);
    // S update: 6 slots over 4 waves, A-operand from kuC registers
    #pragma unroll
    for (int i=0;i<2;i++){
      int tid = w + 4*i;
      if (tid < 6){
        int mt = tid;
        f32x4 acc = (f32x4){0.f,0.f,0.f,0.f};
        #pragma unroll
        for (int ks=0;ks<2;ks++){
          bf16x8 Bv = *(const bf16x8*)&vnewT[l16*72 + ks*32 + quad*8];
          acc = __builtin_amdgcn_mfma_f32_16x16x32_bf16(*(const bf16x8*)&kuC[i][ks], Bv, acc,0,0,0);
        }
        f32x4 ns;
        ns.x = Sreg[i].x*aexpC + acc.x;
        ns.y = Sreg[i].y*aexpC + acc.y;
        ns.z = Sreg[i].z*aexpC + acc.z;
        ns.w = Sreg[i].w*aexpC + acc.w;
        Sreg[i] = ns;
        u32x2 pv;
        pv.x = (u32)f2bf(ns.x) | ((u32)f2bf(ns.y)<<16);
        pv.y = (u32)f2bf(ns.z) | ((u32)f2bf(ns.w)<<16);
        *(u32x2*)&Sbf[l16*104 + mt*16 + quad*4] = pv;
      }
    }
    BAR_LGKM();              // sync2: Sbf visible for next phase 1
    rowb = rowbN; ab = abN;
    edC = edN; aexpC = aexpN;
    kuC[0][0]=kuN[0][0]; kuC[0][1]=kuN[0][1]; kuC[1][0]=kuN[1][0]; kuC[1][1]=kuN[1][1];
  }
}

// ---------------- gated RMSNorm epilogue v2: 8192 blocks, vectorized 8-elem/thread ----------------
__global__ __launch_bounds__(192) void epilogue_kernel(const u16* __restrict__ o,
                                                       const u16* __restrict__ g0, const u16* __restrict__ g1,
                                                       const u16* __restrict__ g2, const u16* __restrict__ g3,
                                                       const void* __restrict__ nw, u16* __restrict__ on,
                                                       const int* __restrict__ flagp){
  const bool f32 = (*flagp != 0);
  const int bl = blockIdx.x;
  const int t = threadIdx.x;
  const int b = bl>>12, l = bl&4095;
  const int h = t/24, d0 = (t - h*24)*8;
  __shared__ float part[192];
  __shared__ float rsS[8];
  u32x4 ov = *(const u32x4*)&o[((size_t)(b*8+h)*4096 + l)*192 + d0];
  float x[8]; unpack8(ov, x);
  float ss = 0.f;
  #pragma unroll
  for (int ch=0;ch<8;ch++) ss += x[ch]*x[ch];
  part[t] = ss;
  __syncthreads();
  if (t < 8){
    float s = 0.f;
    #pragma unroll
    for (int j=0;j<24;j++) s += part[t*24+j];
    rsS[t] = rsqrtf(s/192.f + 1e-5f);
  }
  __syncthreads();
  float rs = rsS[h];
  const u16* gp; int bo;
  if (bl < 5376){ gp = g0; bo = bl; }
  else if (bl < 6656){ gp = g1; bo = bl - 5376; }
  else if (bl < 7680){ gp = g2; bo = bl - 6656; }
  else { gp = g3; bo = bl - 7680; }
  u32x4 gv = *(const u32x4*)&gp[(size_t)bo*1536 + h*192 + d0];
  float gf[8]; unpack8(gv, gf);
  u32x4 nv = ld8bf(nw, d0, f32);
  float nf[8]; unpack8(nv, nf);
  u32x4 pv;
  float r[8];
  #pragma unroll
  for (int ch=0;ch<8;ch++) r[ch] = x[ch]*rs*nf[ch]*gf[ch]*sigx(gf[ch]);
  pv.x = (u32)f2bf(r[0]) | ((u32)f2bf(r[1])<<16);
  pv.y = (u32)f2bf(r[2]) | ((u32)f2bf(r[3])<<16);
  pv.z = (u32)f2bf(r[4]) | ((u32)f2bf(r[5])<<16);
  pv.w = (u32)f2bf(r[6]) | ((u32)f2bf(r[7])<<16);
  *(u32x4*)&on[(size_t)bl*1536 + h*192 + d0] = pv;
}

// ---------------- launch ----------------
extern "C" void kernel_launch(void* const* d_in, const int* in_sizes, int n_in,
                              void* d_out, int out_size, void* d_ws, size_t ws_size,
                              hipStream_t stream){
  (void)in_sizes; (void)n_in; (void)out_size; (void)ws_size;
  const void* u     = d_in[0];
  const void* Wq    = d_in[1];
  const void* Wk    = d_in[2];
  const void* Wv    = d_in[3];
  const void* Wg    = d_in[4];
  const void* Wo    = d_in[5];
  const void* Wgk   = d_in[6];
  const void* Wb    = d_in[7];
  const void* b_b   = d_in[8];
  const void* A_log = d_in[9];
  const void* dt_b  = d_in[10];
  const void* cq    = d_in[11];
  const void* ck    = d_in[12];
  const void* cv    = d_in[13];
  const void* nw    = d_in[14];

  char* w = (char*)d_ws;
  size_t off = 0;
  auto take = [&](size_t bytes)->char*{
    char* p = w + off;
    off += (bytes + 255) & ~(size_t)255;
    return p;
  };
  int* flag = (int*)take(256);
  u16* WqT  = (u16*)take((size_t)768*1024*2);
  u16* WkT  = (u16*)take((size_t)768*1024*2);
  u16* WvT  = (u16*)take((size_t)1536*1024*2);
  u16* WgT  = (u16*)take((size_t)1536*1024*2);
  u16* WoT  = (u16*)take((size_t)1024*1536*2);
  u16* qraw = (u16*)take((size_t)8192*768*2);
  u16* kraw = (u16*)take((size_t)8192*768*2);
  u16* vraw = (u16*)take((size_t)8192*1536*2);
  u16* qn   = (u16*)take((size_t)8192*768*2);
  u16* kn   = (u16*)take((size_t)8192*768*2);   // after chunkprep this region holds kTw (block-local alias)
  u16* vb   = (u16*)take((size_t)8192*1536*2);
  u16* ubf  = (u16*)take((size_t)8192*1024*2);  // bf16 copy of u (A for qkv + glin GEMMs)
  float* gkA   = (float*)take(65536*4);
  float* betaA = (float*)take(65536*4);
  float* edG   = (float*)take(65536*4);
  float* aGA   = (float*)take(1024*4);
  u16* attnA = qraw;
  u16* kcdA  = kraw;
  u16* uuA   = vraw;
  u16* oA    = vb;
  u16* onA   = vraw;
  // glin scratch, 4-way row split (5376/1280/1024/512 rows x 1536 bf16), all dead during the fused kernel:
  u16* glin0 = (u16*)d_out;                       // rows 0..5375
  u16* glin1 = attnA + (size_t)1024*64*64;        // rows 5376..6655 (qraw tail after attn)
  u16* glin2 = WvT;                               // rows 6656..7679 (exact fit)
  u16* glin3 = WkT;                               // rows 7680..8191 (exact fit)

  detect_kernel<<<1,64,0,stream>>>((const u16*)u, flag);
  transpose5<<<8192,256,0,stream>>>(Wq, Wk, Wv, Wg, Wo, u,
                                    WqT, WkT, WvT, WgT, WoT, ubf, flag);
  gemm_qkv<<<1536,256,0,stream>>>(ubf, WqT, WkT, WvT, qraw, kraw, vraw);
  prep_kernel<<<8192,384,0,stream>>>(u, Wgk, Wb, b_b, A_log, dt_b,
                                     qraw, kraw, vraw, cq, ck, cv,
                                     gkA, betaA, qn, kn, vb, flag);
  chunkprep_kernel<<<1024,320,0,stream>>>(qn, kn, vb, betaA, gkA, attnA, kcdA, uuA,
                                          edG, aGA);
  scan_glin_kernel<<<960,256,0,stream>>>(qn, kn /*=kTw*/, kcdA, attnA, uuA, edG, aGA, oA,
                                         ubf, WgT, glin0, glin1, glin2, glin3);
  epilogue_kernel<<<8192,192,0,stream>>>(oA, glin0, glin1, glin2, glin3, nw, onA, flag);
  gemm_bt<<<512,256,0,stream>>>(onA, WoT, d_out, 8192, 1024, 1536, flag, 0, 1, 1);
}

// Round 14
// 547.207 us; speedup vs baseline: 1.1764x; 1.1764x over previous
//
#include <hip/hip_runtime.h>

// ---------------- types / helpers ----------------
using u16 = unsigned short;
using u32 = unsigned int;
typedef __bf16 bf16x8 __attribute__((ext_vector_type(8)));
typedef u16    u16x8  __attribute__((ext_vector_type(8)));
typedef float  f32x4  __attribute__((ext_vector_type(4)));
typedef float  f32x2  __attribute__((ext_vector_type(2)));
typedef u32    u32x4  __attribute__((ext_vector_type(4)));
typedef u32    u32x2  __attribute__((ext_vector_type(2)));

__device__ __forceinline__ float bf2f(u16 h){ u32 u = ((u32)h)<<16; float f; __builtin_memcpy(&f,&u,4); return f; }
__device__ __forceinline__ u16 f2bf(float f){ u32 u; __builtin_memcpy(&u,&f,4); u32 r = (u + 0x7FFFu + ((u>>16)&1u))>>16; return (u16)r; }
__device__ __forceinline__ float bflo(u32 w){ return bf2f((u16)(w & 0xFFFFu)); }
__device__ __forceinline__ float bfhiw(u32 w){ return bf2f((u16)(w >> 16)); }
__device__ __forceinline__ float sigx(float x){ float e = __expf(-fabsf(x)); float p = 1.f/(1.f+e); return (x>=0.f) ? p : 1.f-p; }

// lgkm-only barrier: LDS visibility without draining in-flight global prefetches.
#define BAR_LGKM() asm volatile("s_waitcnt lgkmcnt(0)\n\ts_barrier" ::: "memory")

// dtype-dual loads from EXTERNAL buffers (f32 or bf16)
__device__ __forceinline__ float ldsc(const void* p, size_t i, bool f32){
  return f32 ? ((const float*)p)[i] : bf2f(((const u16*)p)[i]);
}
__device__ __forceinline__ u32x4 ld8bf(const void* p, size_t i, bool f32){
  if (!f32) return *(const u32x4*)((const u16*)p + i);
  const f32x4* q = (const f32x4*)((const float*)p + i);
  f32x4 a = q[0], b = q[1];
  u32x4 r;
  r.x = (u32)f2bf(a.x) | ((u32)f2bf(a.y)<<16);
  r.y = (u32)f2bf(a.z) | ((u32)f2bf(a.w)<<16);
  r.z = (u32)f2bf(b.x) | ((u32)f2bf(b.y)<<16);
  r.w = (u32)f2bf(b.z) | ((u32)f2bf(b.w)<<16);
  return r;
}
__device__ __forceinline__ void unpack8(u32x4 v, float* f){
  f[0]=bflo(v.x); f[1]=bfhiw(v.x); f[2]=bflo(v.y); f[3]=bfhiw(v.y);
  f[4]=bflo(v.z); f[5]=bfhiw(v.z); f[6]=bflo(v.w); f[7]=bfhiw(v.w);
}

// B=2, L=4096, DM=1024, H=8, HQK=96, HV=192, KEY=768, VAL=1536, CHUNK=64, NCH=64

// ---------------- runtime dtype probe ----------------
__global__ void detect_kernel(const u16* __restrict__ probe, int* __restrict__ flag){
  int t = threadIdx.x;
  int bad = 0;
  for (int i=t; i<1024; i+=64){
    u16 h = probe[i];
    int e = (h>>7)&0xFF;
    if (e >= 0xC0) bad = 1;
  }
  unsigned long long anyb = __ballot(bad);
  if (t==0) *flag = (anyb != 0ull) ? 1 : 0;
}

// ---------------- fused weight transposes (5 regions) + u->bf16 copy (one dispatch) ----------------
__global__ void transpose5(const void* __restrict__ Wq, const void* __restrict__ Wk,
                           const void* __restrict__ Wv, const void* __restrict__ Wg,
                           const void* __restrict__ Wo, const void* __restrict__ U,
                           u16* __restrict__ WqT, u16* __restrict__ WkT, u16* __restrict__ WvT,
                           u16* __restrict__ WgT, u16* __restrict__ WoT, u16* __restrict__ ubf,
                           const int* __restrict__ flagp){
  const bool f32 = (*flagp != 0);
  const int bid = blockIdx.x;
  const int t = threadIdx.x;
  if (bid >= 6144){
    size_t base = ((size_t)(bid-6144)*256 + t) * 16;
    u32x4 a = ld8bf(U, base, f32);
    u32x4 b = ld8bf(U, base+8, f32);
    *(u32x4*)(ubf + base)     = a;
    *(u32x4*)(ubf + base + 8) = b;
    return;
  }
  const void* in; u16* out; int C; int local;
  int R;
  if (bid < 768){ in=Wq; out=WqT; R=1024; C=768;  local=bid; }
  else if (bid < 1536){ in=Wk; out=WkT; R=1024; C=768;  local=bid-768; }
  else if (bid < 3072){ in=Wv; out=WvT; R=1024; C=1536; local=bid-1536; }
  else if (bid < 4608){ in=Wg; out=WgT; R=1024; C=1536; local=bid-3072; }
  else { in=Wo; out=WoT; R=1536; C=1024; local=bid-4608; }
  const int nCx = C>>5;
  const int c0 = (local % nCx)*32, r0 = (local / nCx)*32;
  __shared__ u16 tile[32][33];
  int tx = t & 31, ty = t >> 5;
  #pragma unroll
  for (int j=0;j<4;j++){
    int r = r0 + ty + j*8;
    size_t g = (size_t)r*C + c0 + tx;
    tile[ty+j*8][tx] = f32 ? f2bf(((const float*)in)[g]) : ((const u16*)in)[g];
  }
  __syncthreads();
  #pragma unroll
  for (int j=0;j<4;j++){ int c = c0 + ty + j*8; out[(size_t)c*R + r0 + tx] = tile[tx][ty+j*8]; }
}

// ---------------- bf16 MFMA GEMM (final Wo GEMM), 1D grid + XCD swizzle ----------------
__global__ __launch_bounds__(256,2) void gemm_bt(const void* __restrict__ A, const u16* __restrict__ Bt,
                                                 void* __restrict__ C, int M, int N, int K,
                                                 const int* __restrict__ flagp, int a_ext, int c_ext,
                                                 int sanitize){
  __shared__ __align__(16) u16 As[128*32];
  __shared__ __align__(16) u16 Bs[128*32];
  const int fl = *flagp;
  const bool af32 = a_ext && fl;
  const bool cf32 = c_ext && fl;
  const int t = threadIdx.x;
  const int bid = blockIdx.x;
  const int nbn = N>>7, rpx = (M>>7)>>3;
  const int x2 = bid & 7, s = bid >> 3;
  const int bm = (x2*rpx + s/nbn)*128;
  const int bn = (s % nbn)*128;
  const int wave = t>>6, lane = t&63, quad = lane>>4, l16 = lane&15;
  const int wm = (wave>>1)*64, wn = (wave&1)*64;
  f32x4 acc[4][4] = {};
  const int row0 = t>>2, kp = (t&3)*8;
  const size_t iA0 = (size_t)(bm+row0)*K + kp;
  const size_t iA1 = iA0 + (size_t)64*K;
  const u16* pB0 = Bt + (size_t)(bn+row0)*K + kp;
  const u16* pB1 = pB0 + (size_t)64*K;
  u32x4 ra0 = ld8bf(A, iA0, af32);
  u32x4 ra1 = ld8bf(A, iA1, af32);
  u32x4 rb0 = *(const u32x4*)pB0;
  u32x4 rb1 = *(const u32x4*)pB1;
  const int nk = K>>5;
  for (int kt=0; kt<nk; ++kt){
    __syncthreads();
    ((u32x4*)As)[t]     = ra0;
    ((u32x4*)As)[t+256] = ra1;
    ((u32x4*)Bs)[t]     = rb0;
    ((u32x4*)Bs)[t+256] = rb1;
    __syncthreads();
    if (kt+1 < nk){
      int o = (kt+1)*32;
      ra0 = ld8bf(A, iA0 + o, af32); ra1 = ld8bf(A, iA1 + o, af32);
      rb0 = *(const u32x4*)(pB0 + o); rb1 = *(const u32x4*)(pB1 + o);
    }
    bf16x8 af[4], bfv[4];
    #pragma unroll
    for (int i=0;i<4;i++){
      af[i]  = *(const bf16x8*)&As[(wm + i*16 + l16)*32 + quad*8];
      bfv[i] = *(const bf16x8*)&Bs[(wn + i*16 + l16)*32 + quad*8];
    }
    #pragma unroll
    for (int i=0;i<4;i++)
      #pragma unroll
      for (int j=0;j<4;j++)
        acc[i][j] = __builtin_amdgcn_mfma_f32_16x16x32_bf16(af[i], bfv[j], acc[i][j], 0,0,0);
  }
  #pragma unroll
  for (int i=0;i<4;i++)
    #pragma unroll
    for (int j=0;j<4;j++)
      #pragma unroll
      for (int r2=0;r2<4;r2++){
        int m = bm + wm + i*16 + quad*4 + r2;
        int n = bn + wn + j*16 + l16;
        float v = acc[i][j][r2];
        if (sanitize && !(v==v && v<1e30f && v>-1e30f)) v = 0.f;
        if (cf32) ((float*)C)[(size_t)m*N + n] = v;
        else      ((u16*)C)[(size_t)m*N + n] = f2bf(v);
      }
}

// ---------------- q/k/v projection GEMMs, pure (round-9 mapping, bid%8 XCD swizzle) ----------------
__global__ __launch_bounds__(256,2) void gemm_qkv(const u16* __restrict__ A,
                                                  const u16* __restrict__ BtQ, const u16* __restrict__ BtK,
                                                  const u16* __restrict__ BtV,
                                                  u16* __restrict__ Cq, u16* __restrict__ Ck, u16* __restrict__ Cv){
  __shared__ __align__(16) u16 As[128*32];
  __shared__ __align__(16) u16 Bs[128*32];
  const int t = threadIdx.x;
  const int bid = blockIdx.x;                 // 0..1535
  const int x2 = bid & 7, s = bid >> 3;       // s 0..191
  const int bm = (x2*8 + s/24)*128;
  const int cgrp = s % 24;
  const u16* Bt; u16* C; int N, bn;
  if (cgrp < 6){ Bt=BtQ; C=Cq; N=768; bn=cgrp*128; }
  else if (cgrp < 12){ Bt=BtK; C=Ck; N=768; bn=(cgrp-6)*128; }
  else { Bt=BtV; C=Cv; N=1536; bn=(cgrp-12)*128; }
  const int K = 1024;
  const int wave = t>>6, lane = t&63, quad = lane>>4, l16 = lane&15;
  const int wm = (wave>>1)*64, wn = (wave&1)*64;
  f32x4 acc[4][4] = {};
  const int row0 = t>>2, kp = (t&3)*8;
  const u16* pA0 = A + (size_t)(bm+row0)*K + kp;
  const u16* pA1 = pA0 + (size_t)64*K;
  const u16* pB0 = Bt + (size_t)(bn+row0)*K + kp;
  const u16* pB1 = pB0 + (size_t)64*K;
  u32x4 ra0 = *(const u32x4*)pA0;
  u32x4 ra1 = *(const u32x4*)pA1;
  u32x4 rb0 = *(const u32x4*)pB0;
  u32x4 rb1 = *(const u32x4*)pB1;
  for (int kt=0; kt<32; ++kt){
    __syncthreads();
    ((u32x4*)As)[t]     = ra0;
    ((u32x4*)As)[t+256] = ra1;
    ((u32x4*)Bs)[t]     = rb0;
    ((u32x4*)Bs)[t+256] = rb1;
    __syncthreads();
    if (kt+1 < 32){
      int o = (kt+1)*32;
      ra0 = *(const u32x4*)(pA0 + o); ra1 = *(const u32x4*)(pA1 + o);
      rb0 = *(const u32x4*)(pB0 + o); rb1 = *(const u32x4*)(pB1 + o);
    }
    bf16x8 af[4], bfv[4];
    #pragma unroll
    for (int i=0;i<4;i++){
      af[i]  = *(const bf16x8*)&As[(wm + i*16 + l16)*32 + quad*8];
      bfv[i] = *(const bf16x8*)&Bs[(wn + i*16 + l16)*32 + quad*8];
    }
    #pragma unroll
    for (int i=0;i<4;i++)
      #pragma unroll
      for (int j=0;j<4;j++)
        acc[i][j] = __builtin_amdgcn_mfma_f32_16x16x32_bf16(af[i], bfv[j], acc[i][j], 0,0,0);
  }
  #pragma unroll
  for (int i=0;i<4;i++)
    #pragma unroll
    for (int j=0;j<4;j++)
      #pragma unroll
      for (int r2=0;r2<4;r2++){
        int m = bm + wm + i*16 + quad*4 + r2;
        int n = bn + wn + j*16 + l16;
        C[(size_t)m*N + n] = f2bf(acc[i][j][r2]);
      }
}

// ---------------- prep v4: gkbeta (f32 fast path) + role-split vectorized convs ----------------
__global__ __launch_bounds__(384) void prep_kernel(
    const void* __restrict__ u, const void* __restrict__ Wgk, const void* __restrict__ Wb,
    const void* __restrict__ b_b, const void* __restrict__ A_log, const void* __restrict__ dt_b,
    const u16* __restrict__ qraw, const u16* __restrict__ kraw, const u16* __restrict__ vraw,
    const void* __restrict__ cq, const void* __restrict__ ck, const void* __restrict__ cv,
    float* __restrict__ gk, float* __restrict__ beta,
    u16* __restrict__ qn, u16* __restrict__ kn, u16* __restrict__ vb,
    const int* __restrict__ flagp){
  const bool f32 = (*flagp != 0);
  const int bl = blockIdx.x;
  const int b = bl>>12, l = bl&4095;
  const int t = threadIdx.x;
  __shared__ float red[4][16];
  __shared__ float sqP[96], skP[96];
  __shared__ float nrmq[8], nrmk[8];
  __shared__ float bS2[8];

  // ---- phase 0: gk/beta on threads 0..255 (f32 fast path; order identical to r9-r13) ----
  if (t < 256){
    float accg[8] = {0,0,0,0,0,0,0,0};
    float accb[8] = {0,0,0,0,0,0,0,0};
    if (f32){
      const float* uf  = (const float*)u + (size_t)bl*1024;
      const float* wgf = (const float*)Wgk;
      const float* wbf = (const float*)Wb;
      for (int d=t; d<1024; d+=256){
        float uv = uf[d];
        f32x4 ga = *(const f32x4*)(wgf + (size_t)d*8);
        f32x4 gb = *(const f32x4*)(wgf + (size_t)d*8 + 4);
        f32x4 ba = *(const f32x4*)(wbf + (size_t)d*8);
        f32x4 bb = *(const f32x4*)(wbf + (size_t)d*8 + 4);
        accg[0] += uv*ga.x; accg[1] += uv*ga.y; accg[2] += uv*ga.z; accg[3] += uv*ga.w;
        accg[4] += uv*gb.x; accg[5] += uv*gb.y; accg[6] += uv*gb.z; accg[7] += uv*gb.w;
        accb[0] += uv*ba.x; accb[1] += uv*ba.y; accb[2] += uv*ba.z; accb[3] += uv*ba.w;
        accb[4] += uv*bb.x; accb[5] += uv*bb.y; accb[6] += uv*bb.z; accb[7] += uv*bb.w;
      }
    } else {
      const u16* uh = (const u16*)u + (size_t)bl*1024;
      for (int d=t; d<1024; d+=256){
        float uv = bf2f(uh[d]);
        u32x4 wg = *(const u32x4*)((const u16*)Wgk + (size_t)d*8);
        u32x4 wb = *(const u32x4*)((const u16*)Wb  + (size_t)d*8);
        accg[0] += uv*bflo(wg.x); accg[1] += uv*bfhiw(wg.x);
        accg[2] += uv*bflo(wg.y); accg[3] += uv*bfhiw(wg.y);
        accg[4] += uv*bflo(wg.z); accg[5] += uv*bfhiw(wg.z);
        accg[6] += uv*bflo(wg.w); accg[7] += uv*bfhiw(wg.w);
        accb[0] += uv*bflo(wb.x); accb[1] += uv*bfhiw(wb.x);
        accb[2] += uv*bflo(wb.y); accb[3] += uv*bfhiw(wb.y);
        accb[4] += uv*bflo(wb.z); accb[5] += uv*bfhiw(wb.z);
        accb[6] += uv*bflo(wb.w); accb[7] += uv*bfhiw(wb.w);
      }
    }
    #pragma unroll
    for (int h=0;h<8;h++){
      #pragma unroll
      for (int off=32; off>=1; off>>=1){
        accg[h] += __shfl_down(accg[h], off);
        accb[h] += __shfl_down(accb[h], off);
      }
    }
    int wv = t>>6, lane = t&63;
    if (lane==0){
      #pragma unroll
      for (int h=0;h<8;h++){ red[wv][h]=accg[h]; red[wv][8+h]=accb[h]; }
    }
  }
  __syncthreads();
  if (t<16){
    float sum = red[0][t]+red[1][t]+red[2][t]+red[3][t];
    if (t<8){
      int h=t;
      float x = sum + ldsc(dt_b, h, f32);
      float sp = (x>20.f) ? x : log1pf(__expf(x));
      gk[(size_t)(b*8+h)*4096 + l] = -__expf(ldsc(A_log, h, f32)) * sp;
    } else {
      int h=t-8;
      float x = sum + ldsc(b_b, h, f32);
      float bv = sigx(x);
      beta[(size_t)(b*8+h)*4096 + l] = bv;
      bS2[h] = bv;
    }
  }
  __syncthreads();

  // ---- role-split vectorized convs (v3 structure, bS2 from LDS) ----
  const int base = b*4096;
  int role, c0;
  if (t < 96){ role=0; c0=t*8; }
  else if (t < 192){ role=1; c0=(t-96)*8; }
  else { role=2; c0=(t-192)*8; }
  const u16* raw = (role==0)? qraw : (role==1)? kraw : vraw;
  const void* cw = (role==0)? cq : (role==1)? ck : cv;
  const int C = (role==2)? 1536 : 768;

  float w[8][4];
  #pragma unroll
  for (int g=0; g<4; g++){
    u32x4 W = ld8bf(cw, (size_t)c0*4 + g*8, f32);
    w[g*2+0][0]=bflo(W.x); w[g*2+0][1]=bfhiw(W.x); w[g*2+0][2]=bflo(W.y); w[g*2+0][3]=bfhiw(W.y);
    w[g*2+1][0]=bflo(W.z); w[g*2+1][1]=bfhiw(W.z); w[g*2+1][2]=bflo(W.w); w[g*2+1][3]=bfhiw(W.w);
  }
  float acc[8];
  #pragma unroll
  for (int ch=0; ch<8; ch++) acc[ch] = 0.f;
  #pragma unroll
  for (int j=0;j<4;j++){
    if (l >= 3-j){
      u32x4 iv = *(const u32x4*)(raw + (size_t)(base+l-3+j)*C + c0);
      float in[8]; unpack8(iv, in);
      #pragma unroll
      for (int ch=0;ch<8;ch++) acc[ch] += in[ch]*w[ch][j];
    }
  }
  #pragma unroll
  for (int ch=0;ch<8;ch++) acc[ch] = acc[ch]*sigx(acc[ch]);

  if (role==2){
    int h = c0/192, d0 = c0 - h*192;
    float bv = bS2[h];
    u32x4 pv;
    pv.x = (u32)f2bf(acc[0]*bv) | ((u32)f2bf(acc[1]*bv)<<16);
    pv.y = (u32)f2bf(acc[2]*bv) | ((u32)f2bf(acc[3]*bv)<<16);
    pv.z = (u32)f2bf(acc[4]*bv) | ((u32)f2bf(acc[5]*bv)<<16);
    pv.w = (u32)f2bf(acc[6]*bv) | ((u32)f2bf(acc[7]*bv)<<16);
    *(u32x4*)&vb[((size_t)(b*8+h)*4096 + l)*192 + d0] = pv;
  } else {
    float ss = 0.f;
    #pragma unroll
    for (int ch=0;ch<8;ch++) ss += acc[ch]*acc[ch];
    if (role==0) sqP[t] = ss; else skP[t-96] = ss;
  }
  __syncthreads();
  if (t < 8){
    float s = 0.f;
    #pragma unroll
    for (int j=0;j<12;j++) s += sqP[t*12+j];
    nrmq[t] = fmaxf(sqrtf(s), 1e-12f);
  } else if (t < 16){
    int h = t-8;
    float s = 0.f;
    #pragma unroll
    for (int j=0;j<12;j++) s += skP[h*12+j];
    nrmk[h] = fmaxf(sqrtf(s), 1e-12f);
  }
  __syncthreads();
  if (role==0){
    int h = c0/96, d0 = c0 - h*96;
    float nr = nrmq[h];
    u32x4 pv;
    pv.x = (u32)f2bf(acc[0]/nr*0.10206207261596575f) | ((u32)f2bf(acc[1]/nr*0.10206207261596575f)<<16);
    pv.y = (u32)f2bf(acc[2]/nr*0.10206207261596575f) | ((u32)f2bf(acc[3]/nr*0.10206207261596575f)<<16);
    pv.z = (u32)f2bf(acc[4]/nr*0.10206207261596575f) | ((u32)f2bf(acc[5]/nr*0.10206207261596575f)<<16);
    pv.w = (u32)f2bf(acc[6]/nr*0.10206207261596575f) | ((u32)f2bf(acc[7]/nr*0.10206207261596575f)<<16);
    *(u32x4*)&qn[((size_t)(b*8+h)*4096 + l)*96 + d0] = pv;
  } else if (role==1){
    int h = c0/96, d0 = c0 - h*96;
    float nr = nrmk[h];
    u32x4 pv;
    pv.x = (u32)f2bf(acc[0]/nr*1.0f) | ((u32)f2bf(acc[1]/nr*1.0f)<<16);
    pv.y = (u32)f2bf(acc[2]/nr*1.0f) | ((u32)f2bf(acc[3]/nr*1.0f)<<16);
    pv.z = (u32)f2bf(acc[4]/nr*1.0f) | ((u32)f2bf(acc[5]/nr*1.0f)<<16);
    pv.w = (u32)f2bf(acc[6]/nr*1.0f) | ((u32)f2bf(acc[7]/nr*1.0f)<<16);
    *(u32x4*)&kn[((size_t)(b*8+h)*4096 + l)*96 + d0] = pv;
  }
}

// ---------------- chunkprep v6: qS dropped (q frags loaded from global) -> LDS 60.2->46.8KB,
// 3 blocks/CU instead of 2. r13 measured chunkprep at 178us, Occupancy 14% (max 31% at
// 2 blocks/CU): the 2016-FMA serial substitution chain + LDS-read stream is wave-starved.
// q fragments are three 16B global loads/thread at the SAME addresses qS held -> bit-identical;
// issued before the staging barrier so HBM/L2 latency hides under kS staging. ----------------
__global__ __launch_bounds__(320,2) void chunkprep_kernel(
    const u16* __restrict__ qn, u16* __restrict__ knw, const u16* __restrict__ vb,
    const float* __restrict__ beta, const float* __restrict__ gk,
    u16* __restrict__ attn, u16* __restrict__ kcd, u16* __restrict__ uA,
    float* __restrict__ edG, float* __restrict__ aG){
  __shared__ __align__(16) u16 kS[64*104];
  __shared__ float M1[64*64];
  __shared__ float M2[64*64];
  __shared__ float bS[64], dS[64], wS2[64];
  const int t = threadIdx.x;
  const int bhn = blockIdx.x;
  const size_t rowb = (size_t)bhn*64;
  const int w = t>>6, l = t&63, l16 = l&15, quad = l>>4;

  // ---- q fragments straight from global (addresses identical to the old qS reads) ----
  u32x4 qFz[3];
  if (t < 256){
    #pragma unroll
    for (int ks=0;ks<3;ks++)
      qFz[ks] = *(const u32x4*)(qn + (rowb + w*16 + l16)*96 + ks*32 + quad*8);
  }

  // ---- stage k only (u32x4), dec/beta ----
  #pragma unroll
  for (int j=0;j<3;j++){
    int v = t + 320*j;
    if (v < 768){
      int rr = v/12, c8 = v - rr*12;
      size_t g = (rowb+rr)*96 + c8*8;
      *(u32x4*)&kS[rr*104 + c8*8] = *(const u32x4*)(knw + g);
    }
  }
  if (t<64){
    bS[t] = beta[rowb+t];
    float g = gk[rowb+t];
    #pragma unroll
    for (int off=1; off<64; off<<=1){
      float xx = __shfl_up(g, off);
      if (t >= off) g += xx;
    }
    dS[t] = g;
    float dl = __shfl(g, 63);
    edG[rowb+t] = __expf(g);
    wS2[t] = __expf(dl - g);
    if (t==0) aG[bhn] = __expf(dl);
  }
  __syncthreads();   // kS staged (kn reads complete), wS2 ready -> safe to overwrite kn with kTw

  for (int idx=t; idx<6144; idx+=320){
    int d = idx>>6, ll = idx&63;
    knw[(size_t)bhn*6144 + idx] = f2bf(bf2f(kS[ll*104 + d])*wS2[ll]);
  }

  float x[64];
  const int mode0 = (t<192) ? 0 : 1;
  const int c0 = (t<192) ? t : (t-192);
  const bool active = (t < 288);
  if (active){
    if (mode0==0){
      #pragma unroll
      for (int i=0;i<64;i++) x[i] = bf2f(vb[(rowb+i)*192 + c0]);
    } else {
      #pragma unroll
      for (int i=0;i<64;i++) x[i] = bS[i]*bf2f(kS[i*104 + c0]);
    }
  }

  if (t < 256){
    bf16x8 kA[3];
    #pragma unroll
    for (int ks=0;ks<3;ks++)
      kA[ks] = *(const bf16x8*)&kS[(w*16+l16)*104 + ks*32 + quad*8];
    const size_t ab = (size_t)bhn*4096;
    #pragma unroll
    for (int nt=0;nt<4;nt++){
      f32x4 aQ = {0.f,0.f,0.f,0.f}, aK = {0.f,0.f,0.f,0.f};
      #pragma unroll
      for (int ks=0;ks<3;ks++){
        bf16x8 Bf = *(const bf16x8*)&kS[(nt*16+l16)*104 + ks*32 + quad*8];
        aQ = __builtin_amdgcn_mfma_f32_16x16x32_bf16(*(const bf16x8*)&qFz[ks], Bf, aQ,0,0,0);
        aK = __builtin_amdgcn_mfma_f32_16x16x32_bf16(kA[ks], Bf, aK,0,0,0);
      }
      #pragma unroll
      for (int r=0;r<4;r++){
        int row = w*16 + quad*4 + r;
        int col = nt*16 + l16;
        float lm = __expf(fminf(dS[row]-dS[col], 0.f));
        attn[ab + row*64 + col] = (col<=row) ? f2bf(aQ[r]*lm) : (u16)0;
        if (col<row){
          float kkb = aK[r]*bS[row];
          M2[row*64+col] = kkb;
          M1[row*64+col] = kkb*lm;
        }
      }
    }
  }
  __syncthreads();

  if (active){
    const float* Mb = (mode0==0) ? M1 : M2;
    #pragma unroll
    for (int i=1;i<64;i++){
      float acc = x[i];
      #pragma unroll
      for (int m=0;m<i;m++) acc -= Mb[i*64+m]*x[m];
      x[i] = acc;
    }
    if (mode0==0){
      #pragma unroll
      for (int i=0;i<64;i++) uA[(rowb+i)*192 + c0] = f2bf(x[i]);
    } else {
      #pragma unroll
      for (int i=0;i<64;i++) kcd[(rowb+i)*96 + c0] = f2bf(x[i]);
    }
  }
}

// ---------------- fused: scan (blocks 0..191) + glin GEMM (blocks 192..959) ----------------
__global__ __launch_bounds__(256,1) void scan_glin_kernel(
    const u16* __restrict__ qn, const u16* __restrict__ kTw, const u16* __restrict__ kcd,
    const u16* __restrict__ attn, const u16* __restrict__ uA,
    const float* __restrict__ edG, const float* __restrict__ aG,
    u16* __restrict__ o,
    const u16* __restrict__ Ag, const u16* __restrict__ Btg,
    u16* __restrict__ Cg0, u16* __restrict__ Cg1, u16* __restrict__ Cg2, u16* __restrict__ Cg3){
  __shared__ __align__(16) char smem[16640];
  const int bid = blockIdx.x;
  const int t = threadIdx.x;

  if (bid >= 192){
    // ---- glin GEMM tile, XCD-swizzled, bf16 A ----
    u16* As = (u16*)smem;
    u16* Bs = (u16*)(smem + 8192);
    const int j = bid - 192;                 // 0..767
    const int x2 = j & 7, s = j >> 3;        // s 0..95
    const int bm = (x2*8 + s/12)*128;
    const int bn = (s % 12)*128;
    const int wave = t>>6, lane = t&63, quad = lane>>4, l16 = lane&15;
    const int wm = (wave>>1)*64, wn = (wave&1)*64;
    f32x4 acc[4][4] = {};
    const int row0 = t>>2, kp = (t&3)*8;
    const u16* pA0 = Ag + (size_t)(bm+row0)*1024 + kp;
    const u16* pA1 = pA0 + (size_t)64*1024;
    const u16* pB0 = Btg + (size_t)(bn+row0)*1024 + kp;
    const u16* pB1 = pB0 + (size_t)64*1024;
    u32x4 ra0 = *(const u32x4*)pA0;
    u32x4 ra1 = *(const u32x4*)pA1;
    u32x4 rb0 = *(const u32x4*)pB0;
    u32x4 rb1 = *(const u32x4*)pB1;
    for (int kt=0; kt<32; ++kt){
      __syncthreads();
      ((u32x4*)As)[t]     = ra0;
      ((u32x4*)As)[t+256] = ra1;
      ((u32x4*)Bs)[t]     = rb0;
      ((u32x4*)Bs)[t+256] = rb1;
      __syncthreads();
      if (kt+1 < 32){
        int o2 = (kt+1)*32;
        ra0 = *(const u32x4*)(pA0 + o2); ra1 = *(const u32x4*)(pA1 + o2);
        rb0 = *(const u32x4*)(pB0 + o2); rb1 = *(const u32x4*)(pB1 + o2);
      }
      bf16x8 af[4], bfv[4];
      #pragma unroll
      for (int i=0;i<4;i++){
        af[i]  = *(const bf16x8*)&As[(wm + i*16 + l16)*32 + quad*8];
        bfv[i] = *(const bf16x8*)&Bs[(wn + i*16 + l16)*32 + quad*8];
      }
      #pragma unroll
      for (int i=0;i<4;i++)
        #pragma unroll
        for (int j2=0;j2<4;j2++)
          acc[i][j2] = __builtin_amdgcn_mfma_f32_16x16x32_bf16(af[i], bfv[j2], acc[i][j2], 0,0,0);
    }
    u16* Cp; int mo;
    if (bm < 5376){ Cp = Cg0; mo = bm; }
    else if (bm < 6656){ Cp = Cg1; mo = bm - 5376; }
    else if (bm < 7680){ Cp = Cg2; mo = bm - 6656; }
    else { Cp = Cg3; mo = bm - 7680; }
    #pragma unroll
    for (int i=0;i<4;i++)
      #pragma unroll
      for (int j2=0;j2<4;j2++)
        #pragma unroll
        for (int r2=0;r2<4;r2++){
          int m = mo + wm + i*16 + quad*4 + r2;
          int n = bn + wn + j2*16 + l16;
          Cp[(size_t)m*1536 + n] = f2bf(acc[i][j2][r2]);
        }
    return;
  }

  // ---- scan (192 blocks; bh = bid%16 so all 12 eg-blocks of a bh share one XCD) ----
  __builtin_amdgcn_s_setprio(1);   // latency-critical: outprioritize co-resident glin waves
  const int bh = bid % 16, eg = bid / 16;
  const int e0 = eg*16;
  const int w = t>>6, l = t&63, l16 = l&15, quad = l>>4;

  u16* vnewT = (u16*)smem;                 // [16*72]
  u16* Sbf   = (u16*)(smem + 2304);        // [16*104]  S^T bf16 [col][d]

  for (int i=t; i<16*104; i+=256) Sbf[i] = 0;

  size_t rowb = (size_t)bh*4096;
  size_t ab   = (size_t)bh*64*4096;

  u32x4 kcdF[3], qF[3], attF[2]; u16 uF[4];
  u32x4 kuC[2][2], kuN[2][2];              // kTw fragments: [slot][ks], current/next
  auto pfAB = [&](size_t rowbN){
    #pragma unroll
    for (int ks=0; ks<3; ks++){
      size_t gg = (rowbN + w*16 + l16)*96 + ks*32 + quad*8;
      kcdF[ks] = *(const u32x4*)(kcd + gg);
      qF[ks]   = *(const u32x4*)(qn + gg);
    }
  };
  auto pfATT = [&](size_t abN){
    #pragma unroll
    for (int ks=0; ks<2; ks++)
      attF[ks] = *(const u32x4*)(attn + abN + (w*16 + l16)*64 + ks*32 + quad*8);
  };
  auto pfU = [&](size_t rowbN){
    #pragma unroll
    for (int r=0;r<4;r++)
      uF[r] = uA[(rowbN + w*16 + quad*4 + r)*192 + e0 + l16];
  };
  auto pfKU = [&](size_t chunkIdx, u32x4 (&dst)[2][2]){
    #pragma unroll
    for (int i=0;i<2;i++){
      int tid = w + 4*i;
      if (tid < 6){
        size_t base = chunkIdx*6144 + (size_t)(tid*16 + l16)*64 + quad*8;
        dst[i][0] = *(const u32x4*)(kTw + base);
        dst[i][1] = *(const u32x4*)(kTw + base + 32);
      }
    }
  };

  // prologue
  pfAB(rowb); pfU(rowb); pfATT(ab);
  pfKU(rowb>>6, kuC);
  f32x4 edC = *(const f32x4*)&edG[rowb + w*16 + quad*4];
  float aexpC = aG[rowb>>6];
  __syncthreads();           // Sbf zeros visible
  f32x4 Sreg[2] = {};

  for (int n=0;n<64;n++){
    const size_t rowbN = rowb + 64;
    const size_t abN = ab + 4096;
    f32x4 edN = {0.f,0.f,0.f,0.f};
    float aexpN = 0.f;
    if (n<63){
      pfKU(rowbN>>6, kuN);
      edN = *(const f32x4*)&edG[rowbN + w*16 + quad*4];
      aexpN = aG[rowbN>>6];
    }
    // phase 1: accA = kcd@S, accQ = q@S
    f32x4 accA = {0.f,0.f,0.f,0.f}, accQ = {0.f,0.f,0.f,0.f};
    #pragma unroll
    for (int ks=0;ks<3;ks++){
      bf16x8 Bf = *(const bf16x8*)&Sbf[l16*104 + ks*32 + quad*8];
      accA = __builtin_amdgcn_mfma_f32_16x16x32_bf16(*(const bf16x8*)&kcdF[ks], Bf, accA,0,0,0);
      accQ = __builtin_amdgcn_mfma_f32_16x16x32_bf16(*(const bf16x8*)&qF[ks],  Bf, accQ,0,0,0);
    }
    #pragma unroll
    for (int r=0;r<4;r++){
      float vn = bf2f(uF[r]) - edC[r]*accA[r];
      vnewT[l16*72 + (w*16+quad*4+r)] = f2bf(vn);
      accQ[r] *= edC[r];
    }
    if (n<63){ pfAB(rowbN); pfU(rowbN); }
    BAR_LGKM();              // sync1: vnewT visible; global prefetches stay in flight
    // phase 2: accQ += attn @ vnew
    #pragma unroll
    for (int ks=0;ks<2;ks++){
      bf16x8 Bv = *(const bf16x8*)&vnewT[l16*72 + ks*32 + quad*8];
      accQ = __builtin_amdgcn_mfma_f32_16x16x32_bf16(*(const bf16x8*)&attF[ks], Bv, accQ,0,0,0);
    }
    #pragma unroll
    for (int r=0;r<4;r++)
      o[(rowb + w*16 + quad*4 + r)*192 + e0 + l16] = f2bf(accQ[r]);
    if (n<63) pfATT(abN);
    // S update: 6 slots over 4 waves, A-operand from kuC registers
    #pragma unroll
    for (int i=0;i<2;i++){
      int tid = w + 4*i;
      if (tid < 6){
        int mt = tid;
        f32x4 acc = (f32x4){0.f,0.f,0.f,0.f};
        #pragma unroll
        for (int ks=0;ks<2;ks++){
          bf16x8 Bv = *(const bf16x8*)&vnewT[l16*72 + ks*32 + quad*8];
          acc = __builtin_amdgcn_mfma_f32_16x16x32_bf16(*(const bf16x8*)&kuC[i][ks], Bv, acc,0,0,0);
        }
        f32x4 ns;
        ns.x = Sreg[i].x*aexpC + acc.x;
        ns.y = Sreg[i].y*aexpC + acc.y;
        ns.z = Sreg[i].z*aexpC + acc.z;
        ns.w = Sreg[i].w*aexpC + acc.w;
        Sreg[i] = ns;
        u32x2 pv;
        pv.x = (u32)f2bf(ns.x) | ((u32)f2bf(ns.y)<<16);
        pv.y = (u32)f2bf(ns.z) | ((u32)f2bf(ns.w)<<16);
        *(u32x2*)&Sbf[l16*104 + mt*16 + quad*4] = pv;
      }
    }
    BAR_LGKM();              // sync2: Sbf visible for next phase 1
    rowb = rowbN; ab = abN;
    edC = edN; aexpC = aexpN;
    kuC[0][0]=kuN[0][0]; kuC[0][1]=kuN[0][1]; kuC[1][0]=kuN[1][0]; kuC[1][1]=kuN[1][1];
  }
}

// ---------------- gated RMSNorm epilogue v2: 8192 blocks, vectorized 8-elem/thread ----------------
__global__ __launch_bounds__(192) void epilogue_kernel(const u16* __restrict__ o,
                                                       const u16* __restrict__ g0, const u16* __restrict__ g1,
                                                       const u16* __restrict__ g2, const u16* __restrict__ g3,
                                                       const void* __restrict__ nw, u16* __restrict__ on,
                                                       const int* __restrict__ flagp){
  const bool f32 = (*flagp != 0);
  const int bl = blockIdx.x;
  const int t = threadIdx.x;
  const int b = bl>>12, l = bl&4095;
  const int h = t/24, d0 = (t - h*24)*8;
  __shared__ float part[192];
  __shared__ float rsS[8];
  u32x4 ov = *(const u32x4*)&o[((size_t)(b*8+h)*4096 + l)*192 + d0];
  float x[8]; unpack8(ov, x);
  float ss = 0.f;
  #pragma unroll
  for (int ch=0;ch<8;ch++) ss += x[ch]*x[ch];
  part[t] = ss;
  __syncthreads();
  if (t < 8){
    float s = 0.f;
    #pragma unroll
    for (int j=0;j<24;j++) s += part[t*24+j];
    rsS[t] = rsqrtf(s/192.f + 1e-5f);
  }
  __syncthreads();
  float rs = rsS[h];
  const u16* gp; int bo;
  if (bl < 5376){ gp = g0; bo = bl; }
  else if (bl < 6656){ gp = g1; bo = bl - 5376; }
  else if (bl < 7680){ gp = g2; bo = bl - 6656; }
  else { gp = g3; bo = bl - 7680; }
  u32x4 gv = *(const u32x4*)&gp[(size_t)bo*1536 + h*192 + d0];
  float gf[8]; unpack8(gv, gf);
  u32x4 nv = ld8bf(nw, d0, f32);
  float nf[8]; unpack8(nv, nf);
  u32x4 pv;
  float r[8];
  #pragma unroll
  for (int ch=0;ch<8;ch++) r[ch] = x[ch]*rs*nf[ch]*gf[ch]*sigx(gf[ch]);
  pv.x = (u32)f2bf(r[0]) | ((u32)f2bf(r[1])<<16);
  pv.y = (u32)f2bf(r[2]) | ((u32)f2bf(r[3])<<16);
  pv.z = (u32)f2bf(r[4]) | ((u32)f2bf(r[5])<<16);
  pv.w = (u32)f2bf(r[6]) | ((u32)f2bf(r[7])<<16);
  *(u32x4*)&on[(size_t)bl*1536 + h*192 + d0] = pv;
}

// ---------------- launch ----------------
extern "C" void kernel_launch(void* const* d_in, const int* in_sizes, int n_in,
                              void* d_out, int out_size, void* d_ws, size_t ws_size,
                              hipStream_t stream){
  (void)in_sizes; (void)n_in; (void)out_size; (void)ws_size;
  const void* u     = d_in[0];
  const void* Wq    = d_in[1];
  const void* Wk    = d_in[2];
  const void* Wv    = d_in[3];
  const void* Wg    = d_in[4];
  const void* Wo    = d_in[5];
  const void* Wgk   = d_in[6];
  const void* Wb    = d_in[7];
  const void* b_b   = d_in[8];
  const void* A_log = d_in[9];
  const void* dt_b  = d_in[10];
  const void* cq    = d_in[11];
  const void* ck    = d_in[12];
  const void* cv    = d_in[13];
  const void* nw    = d_in[14];

  char* w = (char*)d_ws;
  size_t off = 0;
  auto take = [&](size_t bytes)->char*{
    char* p = w + off;
    off += (bytes + 255) & ~(size_t)255;
    return p;
  };
  int* flag = (int*)take(256);
  u16* WqT  = (u16*)take((size_t)768*1024*2);
  u16* WkT  = (u16*)take((size_t)768*1024*2);
  u16* WvT  = (u16*)take((size_t)1536*1024*2);
  u16* WgT  = (u16*)take((size_t)1536*1024*2);
  u16* WoT  = (u16*)take((size_t)1024*1536*2);
  u16* qraw = (u16*)take((size_t)8192*768*2);
  u16* kraw = (u16*)take((size_t)8192*768*2);
  u16* vraw = (u16*)take((size_t)8192*1536*2);
  u16* qn   = (u16*)take((size_t)8192*768*2);
  u16* kn   = (u16*)take((size_t)8192*768*2);   // after chunkprep this region holds kTw (block-local alias)
  u16* vb   = (u16*)take((size_t)8192*1536*2);
  u16* ubf  = (u16*)take((size_t)8192*1024*2);  // bf16 copy of u (A for qkv + glin GEMMs)
  float* gkA   = (float*)take(65536*4);
  float* betaA = (float*)take(65536*4);
  float* edG   = (float*)take(65536*4);
  float* aGA   = (float*)take(1024*4);
  u16* attnA = qraw;
  u16* kcdA  = kraw;
  u16* uuA   = vraw;
  u16* oA    = vb;
  u16* onA   = vraw;
  // glin scratch, 4-way row split (5376/1280/1024/512 rows x 1536 bf16), all dead during the fused kernel:
  u16* glin0 = (u16*)d_out;                       // rows 0..5375
  u16* glin1 = attnA + (size_t)1024*64*64;        // rows 5376..6655 (qraw tail after attn)
  u16* glin2 = WvT;                               // rows 6656..7679 (exact fit)
  u16* glin3 = WkT;                               // rows 7680..8191 (exact fit)

  detect_kernel<<<1,64,0,stream>>>((const u16*)u, flag);
  transpose5<<<8192,256,0,stream>>>(Wq, Wk, Wv, Wg, Wo, u,
                                    WqT, WkT, WvT, WgT, WoT, ubf, flag);
  gemm_qkv<<<1536,256,0,stream>>>(ubf, WqT, WkT, WvT, qraw, kraw, vraw);
  prep_kernel<<<8192,384,0,stream>>>(u, Wgk, Wb, b_b, A_log, dt_b,
                                     qraw, kraw, vraw, cq, ck, cv,
                                     gkA, betaA, qn, kn, vb, flag);
  chunkprep_kernel<<<1024,320,0,stream>>>(qn, kn, vb, betaA, gkA, attnA, kcdA, uuA,
                                          edG, aGA);
  scan_glin_kernel<<<960,256,0,stream>>>(qn, kn /*=kTw*/, kcdA, attnA, uuA, edG, aGA, oA,
                                         ubf, WgT, glin0, glin1, glin2, glin3);
  epilogue_kernel<<<8192,192,0,stream>>>(oA, glin0, glin1, glin2, glin3, nw, onA, flag);
  gemm_bt<<<512,256,0,stream>>>(onA, WoT, d_out, 8192, 1024, 1536, flag, 0, 1, 1);
}

// Round 15
// 521.083 us; speedup vs baseline: 1.2353x; 1.0501x over previous
//
#include <hip/hip_runtime.h>

// ---------------- types / helpers ----------------
using u16 = unsigned short;
using u32 = unsigned int;
typedef __bf16 bf16x8 __attribute__((ext_vector_type(8)));
typedef u16    u16x8  __attribute__((ext_vector_type(8)));
typedef float  f32x4  __attribute__((ext_vector_type(4)));
typedef float  f32x2  __attribute__((ext_vector_type(2)));
typedef u32    u32x4  __attribute__((ext_vector_type(4)));
typedef u32    u32x2  __attribute__((ext_vector_type(2)));

__device__ __forceinline__ float bf2f(u16 h){ u32 u = ((u32)h)<<16; float f; __builtin_memcpy(&f,&u,4); return f; }
__device__ __forceinline__ u16 f2bf(float f){ u32 u; __builtin_memcpy(&u,&f,4); u32 r = (u + 0x7FFFu + ((u>>16)&1u))>>16; return (u16)r; }
__device__ __forceinline__ float bflo(u32 w){ return bf2f((u16)(w & 0xFFFFu)); }
__device__ __forceinline__ float bfhiw(u32 w){ return bf2f((u16)(w >> 16)); }
__device__ __forceinline__ float sigx(float x){ float e = __expf(-fabsf(x)); float p = 1.f/(1.f+e); return (x>=0.f) ? p : 1.f-p; }

// lgkm-only barrier: LDS visibility without draining in-flight global prefetches.
#define BAR_LGKM() asm volatile("s_waitcnt lgkmcnt(0)\n\ts_barrier" ::: "memory")

// dtype-dual loads from EXTERNAL buffers (f32 or bf16)
__device__ __forceinline__ float ldsc(const void* p, size_t i, bool f32){
  return f32 ? ((const float*)p)[i] : bf2f(((const u16*)p)[i]);
}
__device__ __forceinline__ u32x4 ld8bf(const void* p, size_t i, bool f32){
  if (!f32) return *(const u32x4*)((const u16*)p + i);
  const f32x4* q = (const f32x4*)((const float*)p + i);
  f32x4 a = q[0], b = q[1];
  u32x4 r;
  r.x = (u32)f2bf(a.x) | ((u32)f2bf(a.y)<<16);
  r.y = (u32)f2bf(a.z) | ((u32)f2bf(a.w)<<16);
  r.z = (u32)f2bf(b.x) | ((u32)f2bf(b.y)<<16);
  r.w = (u32)f2bf(b.z) | ((u32)f2bf(b.w)<<16);
  return r;
}
__device__ __forceinline__ void unpack8(u32x4 v, float* f){
  f[0]=bflo(v.x); f[1]=bfhiw(v.x); f[2]=bflo(v.y); f[3]=bfhiw(v.y);
  f[4]=bflo(v.z); f[5]=bfhiw(v.z); f[6]=bflo(v.w); f[7]=bfhiw(v.w);
}

// B=2, L=4096, DM=1024, H=8, HQK=96, HV=192, KEY=768, VAL=1536, CHUNK=64, NCH=64

// ---------------- runtime dtype probe ----------------
__global__ void detect_kernel(const u16* __restrict__ probe, int* __restrict__ flag){
  int t = threadIdx.x;
  int bad = 0;
  for (int i=t; i<1024; i+=64){
    u16 h = probe[i];
    int e = (h>>7)&0xFF;
    if (e >= 0xC0) bad = 1;
  }
  unsigned long long anyb = __ballot(bad);
  if (t==0) *flag = (anyb != 0ull) ? 1 : 0;
}

// ---------------- fused: weight transposes (5 regions) + u->bf16 copy + conv-weight->bf16 ----------------
// Blocks 0..6143: weight transposes. 6144..8191: u->bf16 (ubf). 8192..8239: conv weights cq/ck/cv
// -> bf16 (cqb/ckb/cvb) with the SAME f2bf prep previously applied PER BLOCK (8192x redundantly,
// ~230 VALU ops/thread = ~25% of prep's instruction budget). Values bit-identical.
__global__ void transpose5(const void* __restrict__ Wq, const void* __restrict__ Wk,
                           const void* __restrict__ Wv, const void* __restrict__ Wg,
                           const void* __restrict__ Wo, const void* __restrict__ U,
                           const void* __restrict__ CQ, const void* __restrict__ CK,
                           const void* __restrict__ CV,
                           u16* __restrict__ WqT, u16* __restrict__ WkT, u16* __restrict__ WvT,
                           u16* __restrict__ WgT, u16* __restrict__ WoT, u16* __restrict__ ubf,
                           u16* __restrict__ cqb, u16* __restrict__ ckb, u16* __restrict__ cvb,
                           const int* __restrict__ flagp){
  const bool f32 = (*flagp != 0);
  const int bid = blockIdx.x;
  const int t = threadIdx.x;
  if (bid >= 8192){
    int idx = (bid-8192)*256 + t;     // 0..12287
    const void* src; u16* dst; int o2;
    if (idx < 3072){ src=CQ; dst=cqb; o2=idx; }
    else if (idx < 6144){ src=CK; dst=ckb; o2=idx-3072; }
    else { src=CV; dst=cvb; o2=idx-6144; }
    dst[o2] = f32 ? f2bf(((const float*)src)[o2]) : ((const u16*)src)[o2];
    return;
  }
  if (bid >= 6144){
    size_t base = ((size_t)(bid-6144)*256 + t) * 16;
    u32x4 a = ld8bf(U, base, f32);
    u32x4 b = ld8bf(U, base+8, f32);
    *(u32x4*)(ubf + base)     = a;
    *(u32x4*)(ubf + base + 8) = b;
    return;
  }
  const void* in; u16* out; int C; int local;
  int R;
  if (bid < 768){ in=Wq; out=WqT; R=1024; C=768;  local=bid; }
  else if (bid < 1536){ in=Wk; out=WkT; R=1024; C=768;  local=bid-768; }
  else if (bid < 3072){ in=Wv; out=WvT; R=1024; C=1536; local=bid-1536; }
  else if (bid < 4608){ in=Wg; out=WgT; R=1024; C=1536; local=bid-3072; }
  else { in=Wo; out=WoT; R=1536; C=1024; local=bid-4608; }
  const int nCx = C>>5;
  const int c0 = (local % nCx)*32, r0 = (local / nCx)*32;
  __shared__ u16 tile[32][33];
  int tx = t & 31, ty = t >> 5;
  #pragma unroll
  for (int j=0;j<4;j++){
    int r = r0 + ty + j*8;
    size_t g = (size_t)r*C + c0 + tx;
    tile[ty+j*8][tx] = f32 ? f2bf(((const float*)in)[g]) : ((const u16*)in)[g];
  }
  __syncthreads();
  #pragma unroll
  for (int j=0;j<4;j++){ int c = c0 + ty + j*8; out[(size_t)c*R + r0 + tx] = tile[tx][ty+j*8]; }
}

// ---------------- bf16 MFMA GEMM (final Wo GEMM), 1D grid + XCD swizzle ----------------
__global__ __launch_bounds__(256,2) void gemm_bt(const void* __restrict__ A, const u16* __restrict__ Bt,
                                                 void* __restrict__ C, int M, int N, int K,
                                                 const int* __restrict__ flagp, int a_ext, int c_ext,
                                                 int sanitize){
  __shared__ __align__(16) u16 As[128*32];
  __shared__ __align__(16) u16 Bs[128*32];
  const int fl = *flagp;
  const bool af32 = a_ext && fl;
  const bool cf32 = c_ext && fl;
  const int t = threadIdx.x;
  const int bid = blockIdx.x;
  const int nbn = N>>7, rpx = (M>>7)>>3;
  const int x2 = bid & 7, s = bid >> 3;
  const int bm = (x2*rpx + s/nbn)*128;
  const int bn = (s % nbn)*128;
  const int wave = t>>6, lane = t&63, quad = lane>>4, l16 = lane&15;
  const int wm = (wave>>1)*64, wn = (wave&1)*64;
  f32x4 acc[4][4] = {};
  const int row0 = t>>2, kp = (t&3)*8;
  const size_t iA0 = (size_t)(bm+row0)*K + kp;
  const size_t iA1 = iA0 + (size_t)64*K;
  const u16* pB0 = Bt + (size_t)(bn+row0)*K + kp;
  const u16* pB1 = pB0 + (size_t)64*K;
  u32x4 ra0 = ld8bf(A, iA0, af32);
  u32x4 ra1 = ld8bf(A, iA1, af32);
  u32x4 rb0 = *(const u32x4*)pB0;
  u32x4 rb1 = *(const u32x4*)pB1;
  const int nk = K>>5;
  for (int kt=0; kt<nk; ++kt){
    __syncthreads();
    ((u32x4*)As)[t]     = ra0;
    ((u32x4*)As)[t+256] = ra1;
    ((u32x4*)Bs)[t]     = rb0;
    ((u32x4*)Bs)[t+256] = rb1;
    __syncthreads();
    if (kt+1 < nk){
      int o = (kt+1)*32;
      ra0 = ld8bf(A, iA0 + o, af32); ra1 = ld8bf(A, iA1 + o, af32);
      rb0 = *(const u32x4*)(pB0 + o); rb1 = *(const u32x4*)(pB1 + o);
    }
    bf16x8 af[4], bfv[4];
    #pragma unroll
    for (int i=0;i<4;i++){
      af[i]  = *(const bf16x8*)&As[(wm + i*16 + l16)*32 + quad*8];
      bfv[i] = *(const bf16x8*)&Bs[(wn + i*16 + l16)*32 + quad*8];
    }
    #pragma unroll
    for (int i=0;i<4;i++)
      #pragma unroll
      for (int j=0;j<4;j++)
        acc[i][j] = __builtin_amdgcn_mfma_f32_16x16x32_bf16(af[i], bfv[j], acc[i][j], 0,0,0);
  }
  #pragma unroll
  for (int i=0;i<4;i++)
    #pragma unroll
    for (int j=0;j<4;j++)
      #pragma unroll
      for (int r2=0;r2<4;r2++){
        int m = bm + wm + i*16 + quad*4 + r2;
        int n = bn + wn + j*16 + l16;
        float v = acc[i][j][r2];
        if (sanitize && !(v==v && v<1e30f && v>-1e30f)) v = 0.f;
        if (cf32) ((float*)C)[(size_t)m*N + n] = v;
        else      ((u16*)C)[(size_t)m*N + n] = f2bf(v);
      }
}

// ---------------- q/k/v projection GEMMs, pure (round-9 mapping, bid%8 XCD swizzle) ----------------
__global__ __launch_bounds__(256,2) void gemm_qkv(const u16* __restrict__ A,
                                                  const u16* __restrict__ BtQ, const u16* __restrict__ BtK,
                                                  const u16* __restrict__ BtV,
                                                  u16* __restrict__ Cq, u16* __restrict__ Ck, u16* __restrict__ Cv){
  __shared__ __align__(16) u16 As[128*32];
  __shared__ __align__(16) u16 Bs[128*32];
  const int t = threadIdx.x;
  const int bid = blockIdx.x;                 // 0..1535
  const int x2 = bid & 7, s = bid >> 3;       // s 0..191
  const int bm = (x2*8 + s/24)*128;
  const int cgrp = s % 24;
  const u16* Bt; u16* C; int N, bn;
  if (cgrp < 6){ Bt=BtQ; C=Cq; N=768; bn=cgrp*128; }
  else if (cgrp < 12){ Bt=BtK; C=Ck; N=768; bn=(cgrp-6)*128; }
  else { Bt=BtV; C=Cv; N=1536; bn=(cgrp-12)*128; }
  const int K = 1024;
  const int wave = t>>6, lane = t&63, quad = lane>>4, l16 = lane&15;
  const int wm = (wave>>1)*64, wn = (wave&1)*64;
  f32x4 acc[4][4] = {};
  const int row0 = t>>2, kp = (t&3)*8;
  const u16* pA0 = A + (size_t)(bm+row0)*K + kp;
  const u16* pA1 = pA0 + (size_t)64*K;
  const u16* pB0 = Bt + (size_t)(bn+row0)*K + kp;
  const u16* pB1 = pB0 + (size_t)64*K;
  u32x4 ra0 = *(const u32x4*)pA0;
  u32x4 ra1 = *(const u32x4*)pA1;
  u32x4 rb0 = *(const u32x4*)pB0;
  u32x4 rb1 = *(const u32x4*)pB1;
  for (int kt=0; kt<32; ++kt){
    __syncthreads();
    ((u32x4*)As)[t]     = ra0;
    ((u32x4*)As)[t+256] = ra1;
    ((u32x4*)Bs)[t]     = rb0;
    ((u32x4*)Bs)[t+256] = rb1;
    __syncthreads();
    if (kt+1 < 32){
      int o = (kt+1)*32;
      ra0 = *(const u32x4*)(pA0 + o); ra1 = *(const u32x4*)(pA1 + o);
      rb0 = *(const u32x4*)(pB0 + o); rb1 = *(const u32x4*)(pB1 + o);
    }
    bf16x8 af[4], bfv[4];
    #pragma unroll
    for (int i=0;i<4;i++){
      af[i]  = *(const bf16x8*)&As[(wm + i*16 + l16)*32 + quad*8];
      bfv[i] = *(const bf16x8*)&Bs[(wn + i*16 + l16)*32 + quad*8];
    }
    #pragma unroll
    for (int i=0;i<4;i++)
      #pragma unroll
      for (int j=0;j<4;j++)
        acc[i][j] = __builtin_amdgcn_mfma_f32_16x16x32_bf16(af[i], bfv[j], acc[i][j], 0,0,0);
  }
  #pragma unroll
  for (int i=0;i<4;i++)
    #pragma unroll
    for (int j=0;j<4;j++)
      #pragma unroll
      for (int r2=0;r2<4;r2++){
        int m = bm + wm + i*16 + quad*4 + r2;
        int n = bn + wn + j*16 + l16;
        C[(size_t)m*N + n] = f2bf(acc[i][j][r2]);
      }
}

// ---------------- prep v5: gkbeta (f32 fast path) + convs with PRE-CONVERTED bf16 weights ----------------
__global__ __launch_bounds__(384) void prep_kernel(
    const void* __restrict__ u, const void* __restrict__ Wgk, const void* __restrict__ Wb,
    const void* __restrict__ b_b, const void* __restrict__ A_log, const void* __restrict__ dt_b,
    const u16* __restrict__ qraw, const u16* __restrict__ kraw, const u16* __restrict__ vraw,
    const u16* __restrict__ cqb, const u16* __restrict__ ckb, const u16* __restrict__ cvb,
    float* __restrict__ gk, float* __restrict__ beta,
    u16* __restrict__ qn, u16* __restrict__ kn, u16* __restrict__ vb,
    const int* __restrict__ flagp){
  const bool f32 = (*flagp != 0);
  const int bl = blockIdx.x;
  const int b = bl>>12, l = bl&4095;
  const int t = threadIdx.x;
  __shared__ float red[4][16];
  __shared__ float sqP[96], skP[96];
  __shared__ float nrmq[8], nrmk[8];
  __shared__ float bS2[8];

  // ---- phase 0: gk/beta on threads 0..255 (f32 fast path; order identical to r9-r14) ----
  if (t < 256){
    float accg[8] = {0,0,0,0,0,0,0,0};
    float accb[8] = {0,0,0,0,0,0,0,0};
    if (f32){
      const float* uf  = (const float*)u + (size_t)bl*1024;
      const float* wgf = (const float*)Wgk;
      const float* wbf = (const float*)Wb;
      for (int d=t; d<1024; d+=256){
        float uv = uf[d];
        f32x4 ga = *(const f32x4*)(wgf + (size_t)d*8);
        f32x4 gb = *(const f32x4*)(wgf + (size_t)d*8 + 4);
        f32x4 ba = *(const f32x4*)(wbf + (size_t)d*8);
        f32x4 bb = *(const f32x4*)(wbf + (size_t)d*8 + 4);
        accg[0] += uv*ga.x; accg[1] += uv*ga.y; accg[2] += uv*ga.z; accg[3] += uv*ga.w;
        accg[4] += uv*gb.x; accg[5] += uv*gb.y; accg[6] += uv*gb.z; accg[7] += uv*gb.w;
        accb[0] += uv*ba.x; accb[1] += uv*ba.y; accb[2] += uv*ba.z; accb[3] += uv*ba.w;
        accb[4] += uv*bb.x; accb[5] += uv*bb.y; accb[6] += uv*bb.z; accb[7] += uv*bb.w;
      }
    } else {
      const u16* uh = (const u16*)u + (size_t)bl*1024;
      for (int d=t; d<1024; d+=256){
        float uv = bf2f(uh[d]);
        u32x4 wg = *(const u32x4*)((const u16*)Wgk + (size_t)d*8);
        u32x4 wb = *(const u32x4*)((const u16*)Wb  + (size_t)d*8);
        accg[0] += uv*bflo(wg.x); accg[1] += uv*bfhiw(wg.x);
        accg[2] += uv*bflo(wg.y); accg[3] += uv*bfhiw(wg.y);
        accg[4] += uv*bflo(wg.z); accg[5] += uv*bfhiw(wg.z);
        accg[6] += uv*bflo(wg.w); accg[7] += uv*bfhiw(wg.w);
        accb[0] += uv*bflo(wb.x); accb[1] += uv*bfhiw(wb.x);
        accb[2] += uv*bflo(wb.y); accb[3] += uv*bfhiw(wb.y);
        accb[4] += uv*bflo(wb.z); accb[5] += uv*bfhiw(wb.z);
        accb[6] += uv*bflo(wb.w); accb[7] += uv*bfhiw(wb.w);
      }
    }
    #pragma unroll
    for (int h=0;h<8;h++){
      #pragma unroll
      for (int off=32; off>=1; off>>=1){
        accg[h] += __shfl_down(accg[h], off);
        accb[h] += __shfl_down(accb[h], off);
      }
    }
    int wv = t>>6, lane = t&63;
    if (lane==0){
      #pragma unroll
      for (int h=0;h<8;h++){ red[wv][h]=accg[h]; red[wv][8+h]=accb[h]; }
    }
  }
  __syncthreads();
  if (t<16){
    float sum = red[0][t]+red[1][t]+red[2][t]+red[3][t];
    if (t<8){
      int h=t;
      float x = sum + ldsc(dt_b, h, f32);
      float sp = (x>20.f) ? x : log1pf(__expf(x));
      gk[(size_t)(b*8+h)*4096 + l] = -__expf(ldsc(A_log, h, f32)) * sp;
    } else {
      int h=t-8;
      float x = sum + ldsc(b_b, h, f32);
      float bv = sigx(x);
      beta[(size_t)(b*8+h)*4096 + l] = bv;
      bS2[h] = bv;
    }
  }
  __syncthreads();

  // ---- role-split vectorized convs (weights pre-converted bf16: one u32x4 load per 8 channels) ----
  const int base = b*4096;
  int role, c0;
  if (t < 96){ role=0; c0=t*8; }
  else if (t < 192){ role=1; c0=(t-96)*8; }
  else { role=2; c0=(t-192)*8; }
  const u16* raw = (role==0)? qraw : (role==1)? kraw : vraw;
  const u16* cw  = (role==0)? cqb : (role==1)? ckb : cvb;
  const int C = (role==2)? 1536 : 768;

  float w[8][4];
  #pragma unroll
  for (int g=0; g<4; g++){
    u32x4 W = *(const u32x4*)(cw + (size_t)c0*4 + g*8);
    w[g*2+0][0]=bflo(W.x); w[g*2+0][1]=bfhiw(W.x); w[g*2+0][2]=bflo(W.y); w[g*2+0][3]=bfhiw(W.y);
    w[g*2+1][0]=bflo(W.z); w[g*2+1][1]=bfhiw(W.z); w[g*2+1][2]=bflo(W.w); w[g*2+1][3]=bfhiw(W.w);
  }
  float acc[8];
  #pragma unroll
  for (int ch=0; ch<8; ch++) acc[ch] = 0.f;
  #pragma unroll
  for (int j=0;j<4;j++){
    if (l >= 3-j){
      u32x4 iv = *(const u32x4*)(raw + (size_t)(base+l-3+j)*C + c0);
      float in[8]; unpack8(iv, in);
      #pragma unroll
      for (int ch=0;ch<8;ch++) acc[ch] += in[ch]*w[ch][j];
    }
  }
  #pragma unroll
  for (int ch=0;ch<8;ch++) acc[ch] = acc[ch]*sigx(acc[ch]);

  if (role==2){
    int h = c0/192, d0 = c0 - h*192;
    float bv = bS2[h];
    u32x4 pv;
    pv.x = (u32)f2bf(acc[0]*bv) | ((u32)f2bf(acc[1]*bv)<<16);
    pv.y = (u32)f2bf(acc[2]*bv) | ((u32)f2bf(acc[3]*bv)<<16);
    pv.z = (u32)f2bf(acc[4]*bv) | ((u32)f2bf(acc[5]*bv)<<16);
    pv.w = (u32)f2bf(acc[6]*bv) | ((u32)f2bf(acc[7]*bv)<<16);
    *(u32x4*)&vb[((size_t)(b*8+h)*4096 + l)*192 + d0] = pv;
  } else {
    float ss = 0.f;
    #pragma unroll
    for (int ch=0;ch<8;ch++) ss += acc[ch]*acc[ch];
    if (role==0) sqP[t] = ss; else skP[t-96] = ss;
  }
  __syncthreads();
  if (t < 8){
    float s = 0.f;
    #pragma unroll
    for (int j=0;j<12;j++) s += sqP[t*12+j];
    nrmq[t] = fmaxf(sqrtf(s), 1e-12f);
  } else if (t < 16){
    int h = t-8;
    float s = 0.f;
    #pragma unroll
    for (int j=0;j<12;j++) s += skP[h*12+j];
    nrmk[h] = fmaxf(sqrtf(s), 1e-12f);
  }
  __syncthreads();
  if (role==0){
    int h = c0/96, d0 = c0 - h*96;
    float nr = nrmq[h];
    u32x4 pv;
    pv.x = (u32)f2bf(acc[0]/nr*0.10206207261596575f) | ((u32)f2bf(acc[1]/nr*0.10206207261596575f)<<16);
    pv.y = (u32)f2bf(acc[2]/nr*0.10206207261596575f) | ((u32)f2bf(acc[3]/nr*0.10206207261596575f)<<16);
    pv.z = (u32)f2bf(acc[4]/nr*0.10206207261596575f) | ((u32)f2bf(acc[5]/nr*0.10206207261596575f)<<16);
    pv.w = (u32)f2bf(acc[6]/nr*0.10206207261596575f) | ((u32)f2bf(acc[7]/nr*0.10206207261596575f)<<16);
    *(u32x4*)&qn[((size_t)(b*8+h)*4096 + l)*96 + d0] = pv;
  } else if (role==1){
    int h = c0/96, d0 = c0 - h*96;
    float nr = nrmk[h];
    u32x4 pv;
    pv.x = (u32)f2bf(acc[0]/nr*1.0f) | ((u32)f2bf(acc[1]/nr*1.0f)<<16);
    pv.y = (u32)f2bf(acc[2]/nr*1.0f) | ((u32)f2bf(acc[3]/nr*1.0f)<<16);
    pv.z = (u32)f2bf(acc[4]/nr*1.0f) | ((u32)f2bf(acc[5]/nr*1.0f)<<16);
    pv.w = (u32)f2bf(acc[6]/nr*1.0f) | ((u32)f2bf(acc[7]/nr*1.0f)<<16);
    *(u32x4*)&kn[((size_t)(b*8+h)*4096 + l)*96 + d0] = pv;
  }
}

// ---------------- chunkprep v6: qS dropped (q frags from global), LDS 46.8KB -> 3 blocks/CU ----------------
__global__ __launch_bounds__(320,2) void chunkprep_kernel(
    const u16* __restrict__ qn, u16* __restrict__ knw, const u16* __restrict__ vb,
    const float* __restrict__ beta, const float* __restrict__ gk,
    u16* __restrict__ attn, u16* __restrict__ kcd, u16* __restrict__ uA,
    float* __restrict__ edG, float* __restrict__ aG){
  __shared__ __align__(16) u16 kS[64*104];
  __shared__ float M1[64*64];
  __shared__ float M2[64*64];
  __shared__ float bS[64], dS[64], wS2[64];
  const int t = threadIdx.x;
  const int bhn = blockIdx.x;
  const size_t rowb = (size_t)bhn*64;
  const int w = t>>6, l = t&63, l16 = l&15, quad = l>>4;

  // ---- q fragments straight from global (addresses identical to the old qS reads) ----
  u32x4 qFz[3];
  if (t < 256){
    #pragma unroll
    for (int ks=0;ks<3;ks++)
      qFz[ks] = *(const u32x4*)(qn + (rowb + w*16 + l16)*96 + ks*32 + quad*8);
  }

  // ---- stage k only (u32x4), dec/beta ----
  #pragma unroll
  for (int j=0;j<3;j++){
    int v = t + 320*j;
    if (v < 768){
      int rr = v/12, c8 = v - rr*12;
      size_t g = (rowb+rr)*96 + c8*8;
      *(u32x4*)&kS[rr*104 + c8*8] = *(const u32x4*)(knw + g);
    }
  }
  if (t<64){
    bS[t] = beta[rowb+t];
    float g = gk[rowb+t];
    #pragma unroll
    for (int off=1; off<64; off<<=1){
      float xx = __shfl_up(g, off);
      if (t >= off) g += xx;
    }
    dS[t] = g;
    float dl = __shfl(g, 63);
    edG[rowb+t] = __expf(g);
    wS2[t] = __expf(dl - g);
    if (t==0) aG[bhn] = __expf(dl);
  }
  __syncthreads();   // kS staged (kn reads complete), wS2 ready -> safe to overwrite kn with kTw

  for (int idx=t; idx<6144; idx+=320){
    int d = idx>>6, ll = idx&63;
    knw[(size_t)bhn*6144 + idx] = f2bf(bf2f(kS[ll*104 + d])*wS2[ll]);
  }

  float x[64];
  const int mode0 = (t<192) ? 0 : 1;
  const int c0 = (t<192) ? t : (t-192);
  const bool active = (t < 288);
  if (active){
    if (mode0==0){
      #pragma unroll
      for (int i=0;i<64;i++) x[i] = bf2f(vb[(rowb+i)*192 + c0]);
    } else {
      #pragma unroll
      for (int i=0;i<64;i++) x[i] = bS[i]*bf2f(kS[i*104 + c0]);
    }
  }

  if (t < 256){
    bf16x8 kA[3];
    #pragma unroll
    for (int ks=0;ks<3;ks++)
      kA[ks] = *(const bf16x8*)&kS[(w*16+l16)*104 + ks*32 + quad*8];
    const size_t ab = (size_t)bhn*4096;
    #pragma unroll
    for (int nt=0;nt<4;nt++){
      f32x4 aQ = {0.f,0.f,0.f,0.f}, aK = {0.f,0.f,0.f,0.f};
      #pragma unroll
      for (int ks=0;ks<3;ks++){
        bf16x8 Bf = *(const bf16x8*)&kS[(nt*16+l16)*104 + ks*32 + quad*8];
        aQ = __builtin_amdgcn_mfma_f32_16x16x32_bf16(*(const bf16x8*)&qFz[ks], Bf, aQ,0,0,0);
        aK = __builtin_amdgcn_mfma_f32_16x16x32_bf16(kA[ks], Bf, aK,0,0,0);
      }
      #pragma unroll
      for (int r=0;r<4;r++){
        int row = w*16 + quad*4 + r;
        int col = nt*16 + l16;
        float lm = __expf(fminf(dS[row]-dS[col], 0.f));
        attn[ab + row*64 + col] = (col<=row) ? f2bf(aQ[r]*lm) : (u16)0;
        if (col<row){
          float kkb = aK[r]*bS[row];
          M2[row*64+col] = kkb;
          M1[row*64+col] = kkb*lm;
        }
      }
    }
  }
  __syncthreads();

  if (active){
    const float* Mb = (mode0==0) ? M1 : M2;
    #pragma unroll
    for (int i=1;i<64;i++){
      float acc = x[i];
      #pragma unroll
      for (int m=0;m<i;m++) acc -= Mb[i*64+m]*x[m];
      x[i] = acc;
    }
    if (mode0==0){
      #pragma unroll
      for (int i=0;i<64;i++) uA[(rowb+i)*192 + c0] = f2bf(x[i]);
    } else {
      #pragma unroll
      for (int i=0;i<64;i++) kcd[(rowb+i)*96 + c0] = f2bf(x[i]);
    }
  }
}

// ---------------- fused: scan (blocks 0..191) + glin GEMM (blocks 192..959) ----------------
__global__ __launch_bounds__(256,1) void scan_glin_kernel(
    const u16* __restrict__ qn, const u16* __restrict__ kTw, const u16* __restrict__ kcd,
    const u16* __restrict__ attn, const u16* __restrict__ uA,
    const float* __restrict__ edG, const float* __restrict__ aG,
    u16* __restrict__ o,
    const u16* __restrict__ Ag, const u16* __restrict__ Btg,
    u16* __restrict__ Cg0, u16* __restrict__ Cg1, u16* __restrict__ Cg2, u16* __restrict__ Cg3){
  __shared__ __align__(16) char smem[16640];
  const int bid = blockIdx.x;
  const int t = threadIdx.x;

  if (bid >= 192){
    // ---- glin GEMM tile, XCD-swizzled, bf16 A ----
    u16* As = (u16*)smem;
    u16* Bs = (u16*)(smem + 8192);
    const int j = bid - 192;                 // 0..767
    const int x2 = j & 7, s = j >> 3;        // s 0..95
    const int bm = (x2*8 + s/12)*128;
    const int bn = (s % 12)*128;
    const int wave = t>>6, lane = t&63, quad = lane>>4, l16 = lane&15;
    const int wm = (wave>>1)*64, wn = (wave&1)*64;
    f32x4 acc[4][4] = {};
    const int row0 = t>>2, kp = (t&3)*8;
    const u16* pA0 = Ag + (size_t)(bm+row0)*1024 + kp;
    const u16* pA1 = pA0 + (size_t)64*1024;
    const u16* pB0 = Btg + (size_t)(bn+row0)*1024 + kp;
    const u16* pB1 = pB0 + (size_t)64*1024;
    u32x4 ra0 = *(const u32x4*)pA0;
    u32x4 ra1 = *(const u32x4*)pA1;
    u32x4 rb0 = *(const u32x4*)pB0;
    u32x4 rb1 = *(const u32x4*)pB1;
    for (int kt=0; kt<32; ++kt){
      __syncthreads();
      ((u32x4*)As)[t]     = ra0;
      ((u32x4*)As)[t+256] = ra1;
      ((u32x4*)Bs)[t]     = rb0;
      ((u32x4*)Bs)[t+256] = rb1;
      __syncthreads();
      if (kt+1 < 32){
        int o2 = (kt+1)*32;
        ra0 = *(const u32x4*)(pA0 + o2); ra1 = *(const u32x4*)(pA1 + o2);
        rb0 = *(const u32x4*)(pB0 + o2); rb1 = *(const u32x4*)(pB1 + o2);
      }
      bf16x8 af[4], bfv[4];
      #pragma unroll
      for (int i=0;i<4;i++){
        af[i]  = *(const bf16x8*)&As[(wm + i*16 + l16)*32 + quad*8];
        bfv[i] = *(const bf16x8*)&Bs[(wn + i*16 + l16)*32 + quad*8];
      }
      #pragma unroll
      for (int i=0;i<4;i++)
        #pragma unroll
        for (int j2=0;j2<4;j2++)
          acc[i][j2] = __builtin_amdgcn_mfma_f32_16x16x32_bf16(af[i], bfv[j2], acc[i][j2], 0,0,0);
    }
    u16* Cp; int mo;
    if (bm < 5376){ Cp = Cg0; mo = bm; }
    else if (bm < 6656){ Cp = Cg1; mo = bm - 5376; }
    else if (bm < 7680){ Cp = Cg2; mo = bm - 6656; }
    else { Cp = Cg3; mo = bm - 7680; }
    #pragma unroll
    for (int i=0;i<4;i++)
      #pragma unroll
      for (int j2=0;j2<4;j2++)
        #pragma unroll
        for (int r2=0;r2<4;r2++){
          int m = mo + wm + i*16 + quad*4 + r2;
          int n = bn + wn + j2*16 + l16;
          Cp[(size_t)m*1536 + n] = f2bf(acc[i][j2][r2]);
        }
    return;
  }

  // ---- scan (192 blocks; bh = bid%16 so all 12 eg-blocks of a bh share one XCD) ----
  __builtin_amdgcn_s_setprio(1);   // latency-critical: outprioritize co-resident glin waves
  const int bh = bid % 16, eg = bid / 16;
  const int e0 = eg*16;
  const int w = t>>6, l = t&63, l16 = l&15, quad = l>>4;

  u16* vnewT = (u16*)smem;                 // [16*72]
  u16* Sbf   = (u16*)(smem + 2304);        // [16*104]  S^T bf16 [col][d]

  for (int i=t; i<16*104; i+=256) Sbf[i] = 0;

  size_t rowb = (size_t)bh*4096;
  size_t ab   = (size_t)bh*64*4096;

  u32x4 kcdF[3], qF[3], attF[2]; u16 uF[4];
  u32x4 kuC[2][2], kuN[2][2];              // kTw fragments: [slot][ks], current/next
  auto pfAB = [&](size_t rowbN){
    #pragma unroll
    for (int ks=0; ks<3; ks++){
      size_t gg = (rowbN + w*16 + l16)*96 + ks*32 + quad*8;
      kcdF[ks] = *(const u32x4*)(kcd + gg);
      qF[ks]   = *(const u32x4*)(qn + gg);
    }
  };
  auto pfATT = [&](size_t abN){
    #pragma unroll
    for (int ks=0; ks<2; ks++)
      attF[ks] = *(const u32x4*)(attn + abN + (w*16 + l16)*64 + ks*32 + quad*8);
  };
  auto pfU = [&](size_t rowbN){
    #pragma unroll
    for (int r=0;r<4;r++)
      uF[r] = uA[(rowbN + w*16 + quad*4 + r)*192 + e0 + l16];
  };
  auto pfKU = [&](size_t chunkIdx, u32x4 (&dst)[2][2]){
    #pragma unroll
    for (int i=0;i<2;i++){
      int tid = w + 4*i;
      if (tid < 6){
        size_t base = chunkIdx*6144 + (size_t)(tid*16 + l16)*64 + quad*8;
        dst[i][0] = *(const u32x4*)(kTw + base);
        dst[i][1] = *(const u32x4*)(kTw + base + 32);
      }
    }
  };

  // prologue
  pfAB(rowb); pfU(rowb); pfATT(ab);
  pfKU(rowb>>6, kuC);
  f32x4 edC = *(const f32x4*)&edG[rowb + w*16 + quad*4];
  float aexpC = aG[rowb>>6];
  __syncthreads();           // Sbf zeros visible
  f32x4 Sreg[2] = {};

  for (int n=0;n<64;n++){
    const size_t rowbN = rowb + 64;
    const size_t abN = ab + 4096;
    f32x4 edN = {0.f,0.f,0.f,0.f};
    float aexpN = 0.f;
    if (n<63){
      pfKU(rowbN>>6, kuN);
      edN = *(const f32x4*)&edG[rowbN + w*16 + quad*4];
      aexpN = aG[rowbN>>6];
    }
    // phase 1: accA = kcd@S, accQ = q@S
    f32x4 accA = {0.f,0.f,0.f,0.f}, accQ = {0.f,0.f,0.f,0.f};
    #pragma unroll
    for (int ks=0;ks<3;ks++){
      bf16x8 Bf = *(const bf16x8*)&Sbf[l16*104 + ks*32 + quad*8];
      accA = __builtin_amdgcn_mfma_f32_16x16x32_bf16(*(const bf16x8*)&kcdF[ks], Bf, accA,0,0,0);
      accQ = __builtin_amdgcn_mfma_f32_16x16x32_bf16(*(const bf16x8*)&qF[ks],  Bf, accQ,0,0,0);
    }
    #pragma unroll
    for (int r=0;r<4;r++){
      float vn = bf2f(uF[r]) - edC[r]*accA[r];
      vnewT[l16*72 + (w*16+quad*4+r)] = f2bf(vn);
      accQ[r] *= edC[r];
    }
    if (n<63){ pfAB(rowbN); pfU(rowbN); }
    BAR_LGKM();              // sync1: vnewT visible; global prefetches stay in flight
    // phase 2: accQ += attn @ vnew
    #pragma unroll
    for (int ks=0;ks<2;ks++){
      bf16x8 Bv = *(const bf16x8*)&vnewT[l16*72 + ks*32 + quad*8];
      accQ = __builtin_amdgcn_mfma_f32_16x16x32_bf16(*(const bf16x8*)&attF[ks], Bv, accQ,0,0,0);
    }
    #pragma unroll
    for (int r=0;r<4;r++)
      o[(rowb + w*16 + quad*4 + r)*192 + e0 + l16] = f2bf(accQ[r]);
    if (n<63) pfATT(abN);
    // S update: 6 slots over 4 waves, A-operand from kuC registers
    #pragma unroll
    for (int i=0;i<2;i++){
      int tid = w + 4*i;
      if (tid < 6){
        int mt = tid;
        f32x4 acc = (f32x4){0.f,0.f,0.f,0.f};
        #pragma unroll
        for (int ks=0;ks<2;ks++){
          bf16x8 Bv = *(const bf16x8*)&vnewT[l16*72 + ks*32 + quad*8];
          acc = __builtin_amdgcn_mfma_f32_16x16x32_bf16(*(const bf16x8*)&kuC[i][ks], Bv, acc,0,0,0);
        }
        f32x4 ns;
        ns.x = Sreg[i].x*aexpC + acc.x;
        ns.y = Sreg[i].y*aexpC + acc.y;
        ns.z = Sreg[i].z*aexpC + acc.z;
        ns.w = Sreg[i].w*aexpC + acc.w;
        Sreg[i] = ns;
        u32x2 pv;
        pv.x = (u32)f2bf(ns.x) | ((u32)f2bf(ns.y)<<16);
        pv.y = (u32)f2bf(ns.z) | ((u32)f2bf(ns.w)<<16);
        *(u32x2*)&Sbf[l16*104 + mt*16 + quad*4] = pv;
      }
    }
    BAR_LGKM();              // sync2: Sbf visible for next phase 1
    rowb = rowbN; ab = abN;
    edC = edN; aexpC = aexpN;
    kuC[0][0]=kuN[0][0]; kuC[0][1]=kuN[0][1]; kuC[1][0]=kuN[1][0]; kuC[1][1]=kuN[1][1];
  }
}

// ---------------- gated RMSNorm epilogue v2: 8192 blocks, vectorized 8-elem/thread ----------------
__global__ __launch_bounds__(192) void epilogue_kernel(const u16* __restrict__ o,
                                                       const u16* __restrict__ g0, const u16* __restrict__ g1,
                                                       const u16* __restrict__ g2, const u16* __restrict__ g3,
                                                       const void* __restrict__ nw, u16* __restrict__ on,
                                                       const int* __restrict__ flagp){
  const bool f32 = (*flagp != 0);
  const int bl = blockIdx.x;
  const int t = threadIdx.x;
  const int b = bl>>12, l = bl&4095;
  const int h = t/24, d0 = (t - h*24)*8;
  __shared__ float part[192];
  __shared__ float rsS[8];
  u32x4 ov = *(const u32x4*)&o[((size_t)(b*8+h)*4096 + l)*192 + d0];
  float x[8]; unpack8(ov, x);
  float ss = 0.f;
  #pragma unroll
  for (int ch=0;ch<8;ch++) ss += x[ch]*x[ch];
  part[t] = ss;
  __syncthreads();
  if (t < 8){
    float s = 0.f;
    #pragma unroll
    for (int j=0;j<24;j++) s += part[t*24+j];
    rsS[t] = rsqrtf(s/192.f + 1e-5f);
  }
  __syncthreads();
  float rs = rsS[h];
  const u16* gp; int bo;
  if (bl < 5376){ gp = g0; bo = bl; }
  else if (bl < 6656){ gp = g1; bo = bl - 5376; }
  else if (bl < 7680){ gp = g2; bo = bl - 6656; }
  else { gp = g3; bo = bl - 7680; }
  u32x4 gv = *(const u32x4*)&gp[(size_t)bo*1536 + h*192 + d0];
  float gf[8]; unpack8(gv, gf);
  u32x4 nv = ld8bf(nw, d0, f32);
  float nf[8]; unpack8(nv, nf);
  u32x4 pv;
  float r[8];
  #pragma unroll
  for (int ch=0;ch<8;ch++) r[ch] = x[ch]*rs*nf[ch]*gf[ch]*sigx(gf[ch]);
  pv.x = (u32)f2bf(r[0]) | ((u32)f2bf(r[1])<<16);
  pv.y = (u32)f2bf(r[2]) | ((u32)f2bf(r[3])<<16);
  pv.z = (u32)f2bf(r[4]) | ((u32)f2bf(r[5])<<16);
  pv.w = (u32)f2bf(r[6]) | ((u32)f2bf(r[7])<<16);
  *(u32x4*)&on[(size_t)bl*1536 + h*192 + d0] = pv;
}

// ---------------- launch ----------------
extern "C" void kernel_launch(void* const* d_in, const int* in_sizes, int n_in,
                              void* d_out, int out_size, void* d_ws, size_t ws_size,
                              hipStream_t stream){
  (void)in_sizes; (void)n_in; (void)out_size; (void)ws_size;
  const void* u     = d_in[0];
  const void* Wq    = d_in[1];
  const void* Wk    = d_in[2];
  const void* Wv    = d_in[3];
  const void* Wg    = d_in[4];
  const void* Wo    = d_in[5];
  const void* Wgk   = d_in[6];
  const void* Wb    = d_in[7];
  const void* b_b   = d_in[8];
  const void* A_log = d_in[9];
  const void* dt_b  = d_in[10];
  const void* cq    = d_in[11];
  const void* ck    = d_in[12];
  const void* cv    = d_in[13];
  const void* nw    = d_in[14];

  char* w = (char*)d_ws;
  size_t off = 0;
  auto take = [&](size_t bytes)->char*{
    char* p = w + off;
    off += (bytes + 255) & ~(size_t)255;
    return p;
  };
  int* flag = (int*)take(256);
  u16* WqT  = (u16*)take((size_t)768*1024*2);
  u16* WkT  = (u16*)take((size_t)768*1024*2);
  u16* WvT  = (u16*)take((size_t)1536*1024*2);
  u16* WgT  = (u16*)take((size_t)1536*1024*2);
  u16* WoT  = (u16*)take((size_t)1024*1536*2);
  u16* qraw = (u16*)take((size_t)8192*768*2);
  u16* kraw = (u16*)take((size_t)8192*768*2);
  u16* vraw = (u16*)take((size_t)8192*1536*2);
  u16* qn   = (u16*)take((size_t)8192*768*2);
  u16* kn   = (u16*)take((size_t)8192*768*2);   // after chunkprep this region holds kTw (block-local alias)
  u16* vb   = (u16*)take((size_t)8192*1536*2);
  u16* ubf  = (u16*)take((size_t)8192*1024*2);  // bf16 copy of u (A for qkv + glin GEMMs)
  u16* cqb  = (u16*)take(3072*2);               // bf16 conv weights (pre-converted once)
  u16* ckb  = (u16*)take(3072*2);
  u16* cvb  = (u16*)take(6144*2);
  float* gkA   = (float*)take(65536*4);
  float* betaA = (float*)take(65536*4);
  float* edG   = (float*)take(65536*4);
  float* aGA   = (float*)take(1024*4);
  u16* attnA = qraw;
  u16* kcdA  = kraw;
  u16* uuA   = vraw;
  u16* oA    = vb;
  u16* onA   = vraw;
  // glin scratch, 4-way row split (5376/1280/1024/512 rows x 1536 bf16), all dead during the fused kernel:
  u16* glin0 = (u16*)d_out;                       // rows 0..5375
  u16* glin1 = attnA + (size_t)1024*64*64;        // rows 5376..6655 (qraw tail after attn)
  u16* glin2 = WvT;                               // rows 6656..7679 (exact fit)
  u16* glin3 = WkT;                               // rows 7680..8191 (exact fit)

  detect_kernel<<<1,64,0,stream>>>((const u16*)u, flag);
  transpose5<<<8240,256,0,stream>>>(Wq, Wk, Wv, Wg, Wo, u, cq, ck, cv,
                                    WqT, WkT, WvT, WgT, WoT, ubf, cqb, ckb, cvb, flag);
  gemm_qkv<<<1536,256,0,stream>>>(ubf, WqT, WkT, WvT, qraw, kraw, vraw);
  prep_kernel<<<8192,384,0,stream>>>(u, Wgk, Wb, b_b, A_log, dt_b,
                                     qraw, kraw, vraw, cqb, ckb, cvb,
                                     gkA, betaA, qn, kn, vb, flag);
  chunkprep_kernel<<<1024,320,0,stream>>>(qn, kn, vb, betaA, gkA, attnA, kcdA, uuA,
                                          edG, aGA);
  scan_glin_kernel<<<960,256,0,stream>>>(qn, kn /*=kTw*/, kcdA, attnA, uuA, edG, aGA, oA,
                                         ubf, WgT, glin0, glin1, glin2, glin3);
  epilogue_kernel<<<dim3(8192),192,0,stream>>>(oA, glin0, glin1, glin2, glin3, nw, onA, flag);
  gemm_bt<<<512,256,0,stream>>>(onA, WoT, d_out, 8192, 1024, 1536, flag, 0, 1, 1);
}

// Round 16
// 520.398 us; speedup vs baseline: 1.2370x; 1.0013x over previous
//
#include <hip/hip_runtime.h>

// ---------------- types / helpers ----------------
using u16 = unsigned short;
using u32 = unsigned int;
typedef __bf16 bf16x8 __attribute__((ext_vector_type(8)));
typedef u16    u16x8  __attribute__((ext_vector_type(8)));
typedef float  f32x4  __attribute__((ext_vector_type(4)));
typedef float  f32x2  __attribute__((ext_vector_type(2)));
typedef u32    u32x4  __attribute__((ext_vector_type(4)));
typedef u32    u32x2  __attribute__((ext_vector_type(2)));

__device__ __forceinline__ float bf2f(u16 h){ u32 u = ((u32)h)<<16; float f; __builtin_memcpy(&f,&u,4); return f; }
__device__ __forceinline__ u16 f2bf(float f){ u32 u; __builtin_memcpy(&u,&f,4); u32 r = (u + 0x7FFFu + ((u>>16)&1u))>>16; return (u16)r; }
__device__ __forceinline__ float bflo(u32 w){ return bf2f((u16)(w & 0xFFFFu)); }
__device__ __forceinline__ float bfhiw(u32 w){ return bf2f((u16)(w >> 16)); }
__device__ __forceinline__ float sigx(float x){ float e = __expf(-fabsf(x)); float p = 1.f/(1.f+e); return (x>=0.f) ? p : 1.f-p; }

// lgkm-only barrier: LDS visibility without draining in-flight global prefetches.
#define BAR_LGKM() asm volatile("s_waitcnt lgkmcnt(0)\n\ts_barrier" ::: "memory")

// dtype-dual loads from EXTERNAL buffers (f32 or bf16)
__device__ __forceinline__ float ldsc(const void* p, size_t i, bool f32){
  return f32 ? ((const float*)p)[i] : bf2f(((const u16*)p)[i]);
}
__device__ __forceinline__ u32x4 ld8bf(const void* p, size_t i, bool f32){
  if (!f32) return *(const u32x4*)((const u16*)p + i);
  const f32x4* q = (const f32x4*)((const float*)p + i);
  f32x4 a = q[0], b = q[1];
  u32x4 r;
  r.x = (u32)f2bf(a.x) | ((u32)f2bf(a.y)<<16);
  r.y = (u32)f2bf(a.z) | ((u32)f2bf(a.w)<<16);
  r.z = (u32)f2bf(b.x) | ((u32)f2bf(b.y)<<16);
  r.w = (u32)f2bf(b.z) | ((u32)f2bf(b.w)<<16);
  return r;
}
__device__ __forceinline__ void unpack8(u32x4 v, float* f){
  f[0]=bflo(v.x); f[1]=bfhiw(v.x); f[2]=bflo(v.y); f[3]=bfhiw(v.y);
  f[4]=bflo(v.z); f[5]=bfhiw(v.z); f[6]=bflo(v.w); f[7]=bfhiw(v.w);
}

// B=2, L=4096, DM=1024, H=8, HQK=96, HV=192, KEY=768, VAL=1536, CHUNK=64, NCH=64

// ---------------- runtime dtype probe ----------------
__global__ void detect_kernel(const u16* __restrict__ probe, int* __restrict__ flag){
  int t = threadIdx.x;
  int bad = 0;
  for (int i=t; i<1024; i+=64){
    u16 h = probe[i];
    int e = (h>>7)&0xFF;
    if (e >= 0xC0) bad = 1;
  }
  unsigned long long anyb = __ballot(bad);
  if (t==0) *flag = (anyb != 0ull) ? 1 : 0;
}

// ---------------- fused: weight transposes (5 regions) + u->bf16 copy + conv-weight->bf16 ----------------
__global__ void transpose5(const void* __restrict__ Wq, const void* __restrict__ Wk,
                           const void* __restrict__ Wv, const void* __restrict__ Wg,
                           const void* __restrict__ Wo, const void* __restrict__ U,
                           const void* __restrict__ CQ, const void* __restrict__ CK,
                           const void* __restrict__ CV,
                           u16* __restrict__ WqT, u16* __restrict__ WkT, u16* __restrict__ WvT,
                           u16* __restrict__ WgT, u16* __restrict__ WoT, u16* __restrict__ ubf,
                           u16* __restrict__ cqb, u16* __restrict__ ckb, u16* __restrict__ cvb,
                           const int* __restrict__ flagp){
  const bool f32 = (*flagp != 0);
  const int bid = blockIdx.x;
  const int t = threadIdx.x;
  if (bid >= 8192){
    int idx = (bid-8192)*256 + t;     // 0..12287
    const void* src; u16* dst; int o2;
    if (idx < 3072){ src=CQ; dst=cqb; o2=idx; }
    else if (idx < 6144){ src=CK; dst=ckb; o2=idx-3072; }
    else { src=CV; dst=cvb; o2=idx-6144; }
    dst[o2] = f32 ? f2bf(((const float*)src)[o2]) : ((const u16*)src)[o2];
    return;
  }
  if (bid >= 6144){
    size_t base = ((size_t)(bid-6144)*256 + t) * 16;
    u32x4 a = ld8bf(U, base, f32);
    u32x4 b = ld8bf(U, base+8, f32);
    *(u32x4*)(ubf + base)     = a;
    *(u32x4*)(ubf + base + 8) = b;
    return;
  }
  const void* in; u16* out; int C; int local;
  int R;
  if (bid < 768){ in=Wq; out=WqT; R=1024; C=768;  local=bid; }
  else if (bid < 1536){ in=Wk; out=WkT; R=1024; C=768;  local=bid-768; }
  else if (bid < 3072){ in=Wv; out=WvT; R=1024; C=1536; local=bid-1536; }
  else if (bid < 4608){ in=Wg; out=WgT; R=1024; C=1536; local=bid-3072; }
  else { in=Wo; out=WoT; R=1536; C=1024; local=bid-4608; }
  const int nCx = C>>5;
  const int c0 = (local % nCx)*32, r0 = (local / nCx)*32;
  __shared__ u16 tile[32][33];
  int tx = t & 31, ty = t >> 5;
  #pragma unroll
  for (int j=0;j<4;j++){
    int r = r0 + ty + j*8;
    size_t g = (size_t)r*C + c0 + tx;
    tile[ty+j*8][tx] = f32 ? f2bf(((const float*)in)[g]) : ((const u16*)in)[g];
  }
  __syncthreads();
  #pragma unroll
  for (int j=0;j<4;j++){ int c = c0 + ty + j*8; out[(size_t)c*R + r0 + tx] = tile[tx][ty+j*8]; }
}

// ---------------- bf16 MFMA GEMM (final Wo GEMM), 1D grid + XCD swizzle ----------------
__global__ __launch_bounds__(256,2) void gemm_bt(const void* __restrict__ A, const u16* __restrict__ Bt,
                                                 void* __restrict__ C, int M, int N, int K,
                                                 const int* __restrict__ flagp, int a_ext, int c_ext,
                                                 int sanitize){
  __shared__ __align__(16) u16 As[128*32];
  __shared__ __align__(16) u16 Bs[128*32];
  const int fl = *flagp;
  const bool af32 = a_ext && fl;
  const bool cf32 = c_ext && fl;
  const int t = threadIdx.x;
  const int bid = blockIdx.x;
  const int nbn = N>>7, rpx = (M>>7)>>3;
  const int x2 = bid & 7, s = bid >> 3;
  const int bm = (x2*rpx + s/nbn)*128;
  const int bn = (s % nbn)*128;
  const int wave = t>>6, lane = t&63, quad = lane>>4, l16 = lane&15;
  const int wm = (wave>>1)*64, wn = (wave&1)*64;
  f32x4 acc[4][4] = {};
  const int row0 = t>>2, kp = (t&3)*8;
  const size_t iA0 = (size_t)(bm+row0)*K + kp;
  const size_t iA1 = iA0 + (size_t)64*K;
  const u16* pB0 = Bt + (size_t)(bn+row0)*K + kp;
  const u16* pB1 = pB0 + (size_t)64*K;
  u32x4 ra0 = ld8bf(A, iA0, af32);
  u32x4 ra1 = ld8bf(A, iA1, af32);
  u32x4 rb0 = *(const u32x4*)pB0;
  u32x4 rb1 = *(const u32x4*)pB1;
  const int nk = K>>5;
  for (int kt=0; kt<nk; ++kt){
    __syncthreads();
    ((u32x4*)As)[t]     = ra0;
    ((u32x4*)As)[t+256] = ra1;
    ((u32x4*)Bs)[t]     = rb0;
    ((u32x4*)Bs)[t+256] = rb1;
    __syncthreads();
    if (kt+1 < nk){
      int o = (kt+1)*32;
      ra0 = ld8bf(A, iA0 + o, af32); ra1 = ld8bf(A, iA1 + o, af32);
      rb0 = *(const u32x4*)(pB0 + o); rb1 = *(const u32x4*)(pB1 + o);
    }
    bf16x8 af[4], bfv[4];
    #pragma unroll
    for (int i=0;i<4;i++){
      af[i]  = *(const bf16x8*)&As[(wm + i*16 + l16)*32 + quad*8];
      bfv[i] = *(const bf16x8*)&Bs[(wn + i*16 + l16)*32 + quad*8];
    }
    #pragma unroll
    for (int i=0;i<4;i++)
      #pragma unroll
      for (int j=0;j<4;j++)
        acc[i][j] = __builtin_amdgcn_mfma_f32_16x16x32_bf16(af[i], bfv[j], acc[i][j], 0,0,0);
  }
  #pragma unroll
  for (int i=0;i<4;i++)
    #pragma unroll
    for (int j=0;j<4;j++)
      #pragma unroll
      for (int r2=0;r2<4;r2++){
        int m = bm + wm + i*16 + quad*4 + r2;
        int n = bn + wn + j*16 + l16;
        float v = acc[i][j][r2];
        if (sanitize && !(v==v && v<1e30f && v>-1e30f)) v = 0.f;
        if (cf32) ((float*)C)[(size_t)m*N + n] = v;
        else      ((u16*)C)[(size_t)m*N + n] = f2bf(v);
      }
}

// ---------------- q/k/v projection GEMMs, pure (round-9 mapping, bid%8 XCD swizzle) ----------------
__global__ __launch_bounds__(256,2) void gemm_qkv(const u16* __restrict__ A,
                                                  const u16* __restrict__ BtQ, const u16* __restrict__ BtK,
                                                  const u16* __restrict__ BtV,
                                                  u16* __restrict__ Cq, u16* __restrict__ Ck, u16* __restrict__ Cv){
  __shared__ __align__(16) u16 As[128*32];
  __shared__ __align__(16) u16 Bs[128*32];
  const int t = threadIdx.x;
  const int bid = blockIdx.x;                 // 0..1535
  const int x2 = bid & 7, s = bid >> 3;       // s 0..191
  const int bm = (x2*8 + s/24)*128;
  const int cgrp = s % 24;
  const u16* Bt; u16* C; int N, bn;
  if (cgrp < 6){ Bt=BtQ; C=Cq; N=768; bn=cgrp*128; }
  else if (cgrp < 12){ Bt=BtK; C=Ck; N=768; bn=(cgrp-6)*128; }
  else { Bt=BtV; C=Cv; N=1536; bn=(cgrp-12)*128; }
  const int K = 1024;
  const int wave = t>>6, lane = t&63, quad = lane>>4, l16 = lane&15;
  const int wm = (wave>>1)*64, wn = (wave&1)*64;
  f32x4 acc[4][4] = {};
  const int row0 = t>>2, kp = (t&3)*8;
  const u16* pA0 = A + (size_t)(bm+row0)*K + kp;
  const u16* pA1 = pA0 + (size_t)64*K;
  const u16* pB0 = Bt + (size_t)(bn+row0)*K + kp;
  const u16* pB1 = pB0 + (size_t)64*K;
  u32x4 ra0 = *(const u32x4*)pA0;
  u32x4 ra1 = *(const u32x4*)pA1;
  u32x4 rb0 = *(const u32x4*)pB0;
  u32x4 rb1 = *(const u32x4*)pB1;
  for (int kt=0; kt<32; ++kt){
    __syncthreads();
    ((u32x4*)As)[t]     = ra0;
    ((u32x4*)As)[t+256] = ra1;
    ((u32x4*)Bs)[t]     = rb0;
    ((u32x4*)Bs)[t+256] = rb1;
    __syncthreads();
    if (kt+1 < 32){
      int o = (kt+1)*32;
      ra0 = *(const u32x4*)(pA0 + o); ra1 = *(const u32x4*)(pA1 + o);
      rb0 = *(const u32x4*)(pB0 + o); rb1 = *(const u32x4*)(pB1 + o);
    }
    bf16x8 af[4], bfv[4];
    #pragma unroll
    for (int i=0;i<4;i++){
      af[i]  = *(const bf16x8*)&As[(wm + i*16 + l16)*32 + quad*8];
      bfv[i] = *(const bf16x8*)&Bs[(wn + i*16 + l16)*32 + quad*8];
    }
    #pragma unroll
    for (int i=0;i<4;i++)
      #pragma unroll
      for (int j=0;j<4;j++)
        acc[i][j] = __builtin_amdgcn_mfma_f32_16x16x32_bf16(af[i], bfv[j], acc[i][j], 0,0,0);
  }
  #pragma unroll
  for (int i=0;i<4;i++)
    #pragma unroll
    for (int j=0;j<4;j++)
      #pragma unroll
      for (int r2=0;r2<4;r2++){
        int m = bm + wm + i*16 + quad*4 + r2;
        int n = bn + wn + j*16 + l16;
        C[(size_t)m*N + n] = f2bf(acc[i][j][r2]);
      }
}

// ---------------- prep v5: gkbeta (f32 fast path) + convs with PRE-CONVERTED bf16 weights ----------------
__global__ __launch_bounds__(384) void prep_kernel(
    const void* __restrict__ u, const void* __restrict__ Wgk, const void* __restrict__ Wb,
    const void* __restrict__ b_b, const void* __restrict__ A_log, const void* __restrict__ dt_b,
    const u16* __restrict__ qraw, const u16* __restrict__ kraw, const u16* __restrict__ vraw,
    const u16* __restrict__ cqb, const u16* __restrict__ ckb, const u16* __restrict__ cvb,
    float* __restrict__ gk, float* __restrict__ beta,
    u16* __restrict__ qn, u16* __restrict__ kn, u16* __restrict__ vb,
    const int* __restrict__ flagp){
  const bool f32 = (*flagp != 0);
  const int bl = blockIdx.x;
  const int b = bl>>12, l = bl&4095;
  const int t = threadIdx.x;
  __shared__ float red[4][16];
  __shared__ float sqP[96], skP[96];
  __shared__ float nrmq[8], nrmk[8];
  __shared__ float bS2[8];

  if (t < 256){
    float accg[8] = {0,0,0,0,0,0,0,0};
    float accb[8] = {0,0,0,0,0,0,0,0};
    if (f32){
      const float* uf  = (const float*)u + (size_t)bl*1024;
      const float* wgf = (const float*)Wgk;
      const float* wbf = (const float*)Wb;
      for (int d=t; d<1024; d+=256){
        float uv = uf[d];
        f32x4 ga = *(const f32x4*)(wgf + (size_t)d*8);
        f32x4 gb = *(const f32x4*)(wgf + (size_t)d*8 + 4);
        f32x4 ba = *(const f32x4*)(wbf + (size_t)d*8);
        f32x4 bb = *(const f32x4*)(wbf + (size_t)d*8 + 4);
        accg[0] += uv*ga.x; accg[1] += uv*ga.y; accg[2] += uv*ga.z; accg[3] += uv*ga.w;
        accg[4] += uv*gb.x; accg[5] += uv*gb.y; accg[6] += uv*gb.z; accg[7] += uv*gb.w;
        accb[0] += uv*ba.x; accb[1] += uv*ba.y; accb[2] += uv*ba.z; accb[3] += uv*ba.w;
        accb[4] += uv*bb.x; accb[5] += uv*bb.y; accb[6] += uv*bb.z; accb[7] += uv*bb.w;
      }
    } else {
      const u16* uh = (const u16*)u + (size_t)bl*1024;
      for (int d=t; d<1024; d+=256){
        float uv = bf2f(uh[d]);
        u32x4 wg = *(const u32x4*)((const u16*)Wgk + (size_t)d*8);
        u32x4 wb = *(const u32x4*)((const u16*)Wb  + (size_t)d*8);
        accg[0] += uv*bflo(wg.x); accg[1] += uv*bfhiw(wg.x);
        accg[2] += uv*bflo(wg.y); accg[3] += uv*bfhiw(wg.y);
        accg[4] += uv*bflo(wg.z); accg[5] += uv*bfhiw(wg.z);
        accg[6] += uv*bflo(wg.w); accg[7] += uv*bfhiw(wg.w);
        accb[0] += uv*bflo(wb.x); accb[1] += uv*bfhiw(wb.x);
        accb[2] += uv*bflo(wb.y); accb[3] += uv*bfhiw(wb.y);
        accb[4] += uv*bflo(wb.z); accb[5] += uv*bfhiw(wb.z);
        accb[6] += uv*bflo(wb.w); accb[7] += uv*bfhiw(wb.w);
      }
    }
    #pragma unroll
    for (int h=0;h<8;h++){
      #pragma unroll
      for (int off=32; off>=1; off>>=1){
        accg[h] += __shfl_down(accg[h], off);
        accb[h] += __shfl_down(accb[h], off);
      }
    }
    int wv = t>>6, lane = t&63;
    if (lane==0){
      #pragma unroll
      for (int h=0;h<8;h++){ red[wv][h]=accg[h]; red[wv][8+h]=accb[h]; }
    }
  }
  __syncthreads();
  if (t<16){
    float sum = red[0][t]+red[1][t]+red[2][t]+red[3][t];
    if (t<8){
      int h=t;
      float x = sum + ldsc(dt_b, h, f32);
      float sp = (x>20.f) ? x : log1pf(__expf(x));
      gk[(size_t)(b*8+h)*4096 + l] = -__expf(ldsc(A_log, h, f32)) * sp;
    } else {
      int h=t-8;
      float x = sum + ldsc(b_b, h, f32);
      float bv = sigx(x);
      beta[(size_t)(b*8+h)*4096 + l] = bv;
      bS2[h] = bv;
    }
  }
  __syncthreads();

  const int base = b*4096;
  int role, c0;
  if (t < 96){ role=0; c0=t*8; }
  else if (t < 192){ role=1; c0=(t-96)*8; }
  else { role=2; c0=(t-192)*8; }
  const u16* raw = (role==0)? qraw : (role==1)? kraw : vraw;
  const u16* cw  = (role==0)? cqb : (role==1)? ckb : cvb;
  const int C = (role==2)? 1536 : 768;

  float w[8][4];
  #pragma unroll
  for (int g=0; g<4; g++){
    u32x4 W = *(const u32x4*)(cw + (size_t)c0*4 + g*8);
    w[g*2+0][0]=bflo(W.x); w[g*2+0][1]=bfhiw(W.x); w[g*2+0][2]=bflo(W.y); w[g*2+0][3]=bfhiw(W.y);
    w[g*2+1][0]=bflo(W.z); w[g*2+1][1]=bfhiw(W.z); w[g*2+1][2]=bflo(W.w); w[g*2+1][3]=bfhiw(W.w);
  }
  float acc[8];
  #pragma unroll
  for (int ch=0; ch<8; ch++) acc[ch] = 0.f;
  #pragma unroll
  for (int j=0;j<4;j++){
    if (l >= 3-j){
      u32x4 iv = *(const u32x4*)(raw + (size_t)(base+l-3+j)*C + c0);
      float in[8]; unpack8(iv, in);
      #pragma unroll
      for (int ch=0;ch<8;ch++) acc[ch] += in[ch]*w[ch][j];
    }
  }
  #pragma unroll
  for (int ch=0;ch<8;ch++) acc[ch] = acc[ch]*sigx(acc[ch]);

  if (role==2){
    int h = c0/192, d0 = c0 - h*192;
    float bv = bS2[h];
    u32x4 pv;
    pv.x = (u32)f2bf(acc[0]*bv) | ((u32)f2bf(acc[1]*bv)<<16);
    pv.y = (u32)f2bf(acc[2]*bv) | ((u32)f2bf(acc[3]*bv)<<16);
    pv.z = (u32)f2bf(acc[4]*bv) | ((u32)f2bf(acc[5]*bv)<<16);
    pv.w = (u32)f2bf(acc[6]*bv) | ((u32)f2bf(acc[7]*bv)<<16);
    *(u32x4*)&vb[((size_t)(b*8+h)*4096 + l)*192 + d0] = pv;
  } else {
    float ss = 0.f;
    #pragma unroll
    for (int ch=0;ch<8;ch++) ss += acc[ch]*acc[ch];
    if (role==0) sqP[t] = ss; else skP[t-96] = ss;
  }
  __syncthreads();
  if (t < 8){
    float s = 0.f;
    #pragma unroll
    for (int j=0;j<12;j++) s += sqP[t*12+j];
    nrmq[t] = fmaxf(sqrtf(s), 1e-12f);
  } else if (t < 16){
    int h = t-8;
    float s = 0.f;
    #pragma unroll
    for (int j=0;j<12;j++) s += skP[h*12+j];
    nrmk[h] = fmaxf(sqrtf(s), 1e-12f);
  }
  __syncthreads();
  if (role==0){
    int h = c0/96, d0 = c0 - h*96;
    float nr = nrmq[h];
    u32x4 pv;
    pv.x = (u32)f2bf(acc[0]/nr*0.10206207261596575f) | ((u32)f2bf(acc[1]/nr*0.10206207261596575f)<<16);
    pv.y = (u32)f2bf(acc[2]/nr*0.10206207261596575f) | ((u32)f2bf(acc[3]/nr*0.10206207261596575f)<<16);
    pv.z = (u32)f2bf(acc[4]/nr*0.10206207261596575f) | ((u32)f2bf(acc[5]/nr*0.10206207261596575f)<<16);
    pv.w = (u32)f2bf(acc[6]/nr*0.10206207261596575f) | ((u32)f2bf(acc[7]/nr*0.10206207261596575f)<<16);
    *(u32x4*)&qn[((size_t)(b*8+h)*4096 + l)*96 + d0] = pv;
  } else if (role==1){
    int h = c0/96, d0 = c0 - h*96;
    float nr = nrmk[h];
    u32x4 pv;
    pv.x = (u32)f2bf(acc[0]/nr*1.0f) | ((u32)f2bf(acc[1]/nr*1.0f)<<16);
    pv.y = (u32)f2bf(acc[2]/nr*1.0f) | ((u32)f2bf(acc[3]/nr*1.0f)<<16);
    pv.z = (u32)f2bf(acc[4]/nr*1.0f) | ((u32)f2bf(acc[5]/nr*1.0f)<<16);
    pv.w = (u32)f2bf(acc[6]/nr*1.0f) | ((u32)f2bf(acc[7]/nr*1.0f)<<16);
    *(u32x4*)&kn[((size_t)(b*8+h)*4096 + l)*96 + d0] = pv;
  }
}

// ---------------- chunkprep v7: triangular M1/M2 packing -> LDS 47.1KB -> ~30.2KB -> 4 blocks/CU ----------------
// r15: LDS 47104 capped residency at 3 blocks/CU (Occupancy 13%, VALUBusy 40%) for the serial
// 2016-FMA substitution chain. Only col<row entries of M1/M2 are ever touched: pack lower-triangular
// (2016 floats each, tri(i)=i(i-1)/2). Triangular offsets are compile-time constants in the fully
// unrolled substitution (static ds_read offsets); runtime mul at the phase-A write. VGPR=100 allows
// 5 waves/SIMD = exactly 4 blocks x 5 waves per CU -> LDS was the only binding constraint.
// Arithmetic, order, values bit-identical (pure layout change).
__global__ __launch_bounds__(320,2) void chunkprep_kernel(
    const u16* __restrict__ qn, u16* __restrict__ knw, const u16* __restrict__ vb,
    const float* __restrict__ beta, const float* __restrict__ gk,
    u16* __restrict__ attn, u16* __restrict__ kcd, u16* __restrict__ uA,
    float* __restrict__ edG, float* __restrict__ aG){
  __shared__ __align__(16) u16 kS[64*104];
  __shared__ float M1[2016];
  __shared__ float M2[2016];
  __shared__ float bS[64], dS[64], wS2[64];
  const int t = threadIdx.x;
  const int bhn = blockIdx.x;
  const size_t rowb = (size_t)bhn*64;
  const int w = t>>6, l = t&63, l16 = l&15, quad = l>>4;

  // ---- q fragments straight from global (addresses identical to the old qS reads) ----
  u32x4 qFz[3];
  if (t < 256){
    #pragma unroll
    for (int ks=0;ks<3;ks++)
      qFz[ks] = *(const u32x4*)(qn + (rowb + w*16 + l16)*96 + ks*32 + quad*8);
  }

  // ---- stage k only (u32x4), dec/beta ----
  #pragma unroll
  for (int j=0;j<3;j++){
    int v = t + 320*j;
    if (v < 768){
      int rr = v/12, c8 = v - rr*12;
      size_t g = (rowb+rr)*96 + c8*8;
      *(u32x4*)&kS[rr*104 + c8*8] = *(const u32x4*)(knw + g);
    }
  }
  if (t<64){
    bS[t] = beta[rowb+t];
    float g = gk[rowb+t];
    #pragma unroll
    for (int off=1; off<64; off<<=1){
      float xx = __shfl_up(g, off);
      if (t >= off) g += xx;
    }
    dS[t] = g;
    float dl = __shfl(g, 63);
    edG[rowb+t] = __expf(g);
    wS2[t] = __expf(dl - g);
    if (t==0) aG[bhn] = __expf(dl);
  }
  __syncthreads();   // kS staged (kn reads complete), wS2 ready -> safe to overwrite kn with kTw

  for (int idx=t; idx<6144; idx+=320){
    int d = idx>>6, ll = idx&63;
    knw[(size_t)bhn*6144 + idx] = f2bf(bf2f(kS[ll*104 + d])*wS2[ll]);
  }

  float x[64];
  const int mode0 = (t<192) ? 0 : 1;
  const int c0 = (t<192) ? t : (t-192);
  const bool active = (t < 288);
  if (active){
    if (mode0==0){
      #pragma unroll
      for (int i=0;i<64;i++) x[i] = bf2f(vb[(rowb+i)*192 + c0]);
    } else {
      #pragma unroll
      for (int i=0;i<64;i++) x[i] = bS[i]*bf2f(kS[i*104 + c0]);
    }
  }

  if (t < 256){
    bf16x8 kA[3];
    #pragma unroll
    for (int ks=0;ks<3;ks++)
      kA[ks] = *(const bf16x8*)&kS[(w*16+l16)*104 + ks*32 + quad*8];
    const size_t ab = (size_t)bhn*4096;
    #pragma unroll
    for (int nt=0;nt<4;nt++){
      f32x4 aQ = {0.f,0.f,0.f,0.f}, aK = {0.f,0.f,0.f,0.f};
      #pragma unroll
      for (int ks=0;ks<3;ks++){
        bf16x8 Bf = *(const bf16x8*)&kS[(nt*16+l16)*104 + ks*32 + quad*8];
        aQ = __builtin_amdgcn_mfma_f32_16x16x32_bf16(*(const bf16x8*)&qFz[ks], Bf, aQ,0,0,0);
        aK = __builtin_amdgcn_mfma_f32_16x16x32_bf16(kA[ks], Bf, aK,0,0,0);
      }
      #pragma unroll
      for (int r=0;r<4;r++){
        int row = w*16 + quad*4 + r;
        int col = nt*16 + l16;
        float lm = __expf(fminf(dS[row]-dS[col], 0.f));
        attn[ab + row*64 + col] = (col<=row) ? f2bf(aQ[r]*lm) : (u16)0;
        if (col<row){
          int tri = (row*(row-1))>>1;
          float kkb = aK[r]*bS[row];
          M2[tri+col] = kkb;
          M1[tri+col] = kkb*lm;
        }
      }
    }
  }
  __syncthreads();

  if (active){
    const float* Mb = (mode0==0) ? M1 : M2;
    #pragma unroll
    for (int i=1;i<64;i++){
      float acc = x[i];
      const int tri = (i*(i-1))>>1;   // compile-time after unroll
      #pragma unroll
      for (int m=0;m<i;m++) acc -= Mb[tri+m]*x[m];
      x[i] = acc;
    }
    if (mode0==0){
      #pragma unroll
      for (int i=0;i<64;i++) uA[(rowb+i)*192 + c0] = f2bf(x[i]);
    } else {
      #pragma unroll
      for (int i=0;i<64;i++) kcd[(rowb+i)*96 + c0] = f2bf(x[i]);
    }
  }
}

// ---------------- fused: scan (blocks 0..191) + glin GEMM (blocks 192..959) ----------------
__global__ __launch_bounds__(256,1) void scan_glin_kernel(
    const u16* __restrict__ qn, const u16* __restrict__ kTw, const u16* __restrict__ kcd,
    const u16* __restrict__ attn, const u16* __restrict__ uA,
    const float* __restrict__ edG, const float* __restrict__ aG,
    u16* __restrict__ o,
    const u16* __restrict__ Ag, const u16* __restrict__ Btg,
    u16* __restrict__ Cg0, u16* __restrict__ Cg1, u16* __restrict__ Cg2, u16* __restrict__ Cg3){
  __shared__ __align__(16) char smem[16640];
  const int bid = blockIdx.x;
  const int t = threadIdx.x;

  if (bid >= 192){
    // ---- glin GEMM tile, XCD-swizzled, bf16 A ----
    u16* As = (u16*)smem;
    u16* Bs = (u16*)(smem + 8192);
    const int j = bid - 192;                 // 0..767
    const int x2 = j & 7, s = j >> 3;        // s 0..95
    const int bm = (x2*8 + s/12)*128;
    const int bn = (s % 12)*128;
    const int wave = t>>6, lane = t&63, quad = lane>>4, l16 = lane&15;
    const int wm = (wave>>1)*64, wn = (wave&1)*64;
    f32x4 acc[4][4] = {};
    const int row0 = t>>2, kp = (t&3)*8;
    const u16* pA0 = Ag + (size_t)(bm+row0)*1024 + kp;
    const u16* pA1 = pA0 + (size_t)64*1024;
    const u16* pB0 = Btg + (size_t)(bn+row0)*1024 + kp;
    const u16* pB1 = pB0 + (size_t)64*1024;
    u32x4 ra0 = *(const u32x4*)pA0;
    u32x4 ra1 = *(const u32x4*)pA1;
    u32x4 rb0 = *(const u32x4*)pB0;
    u32x4 rb1 = *(const u32x4*)pB1;
    for (int kt=0; kt<32; ++kt){
      __syncthreads();
      ((u32x4*)As)[t]     = ra0;
      ((u32x4*)As)[t+256] = ra1;
      ((u32x4*)Bs)[t]     = rb0;
      ((u32x4*)Bs)[t+256] = rb1;
      __syncthreads();
      if (kt+1 < 32){
        int o2 = (kt+1)*32;
        ra0 = *(const u32x4*)(pA0 + o2); ra1 = *(const u32x4*)(pA1 + o2);
        rb0 = *(const u32x4*)(pB0 + o2); rb1 = *(const u32x4*)(pB1 + o2);
      }
      bf16x8 af[4], bfv[4];
      #pragma unroll
      for (int i=0;i<4;i++){
        af[i]  = *(const bf16x8*)&As[(wm + i*16 + l16)*32 + quad*8];
        bfv[i] = *(const bf16x8*)&Bs[(wn + i*16 + l16)*32 + quad*8];
      }
      #pragma unroll
      for (int i=0;i<4;i++)
        #pragma unroll
        for (int j2=0;j2<4;j2++)
          acc[i][j2] = __builtin_amdgcn_mfma_f32_16x16x32_bf16(af[i], bfv[j2], acc[i][j2], 0,0,0);
    }
    u16* Cp; int mo;
    if (bm < 5376){ Cp = Cg0; mo = bm; }
    else if (bm < 6656){ Cp = Cg1; mo = bm - 5376; }
    else if (bm < 7680){ Cp = Cg2; mo = bm - 6656; }
    else { Cp = Cg3; mo = bm - 7680; }
    #pragma unroll
    for (int i=0;i<4;i++)
      #pragma unroll
      for (int j2=0;j2<4;j2++)
        #pragma unroll
        for (int r2=0;r2<4;r2++){
          int m = mo + wm + i*16 + quad*4 + r2;
          int n = bn + wn + j2*16 + l16;
          Cp[(size_t)m*1536 + n] = f2bf(acc[i][j2][r2]);
        }
    return;
  }

  // ---- scan (192 blocks; bh = bid%16 so all 12 eg-blocks of a bh share one XCD) ----
  __builtin_amdgcn_s_setprio(1);   // latency-critical: outprioritize co-resident glin waves
  const int bh = bid % 16, eg = bid / 16;
  const int e0 = eg*16;
  const int w = t>>6, l = t&63, l16 = l&15, quad = l>>4;

  u16* vnewT = (u16*)smem;                 // [16*72]
  u16* Sbf   = (u16*)(smem + 2304);        // [16*104]  S^T bf16 [col][d]

  for (int i=t; i<16*104; i+=256) Sbf[i] = 0;

  size_t rowb = (size_t)bh*4096;
  size_t ab   = (size_t)bh*64*4096;

  u32x4 kcdF[3], qF[3], attF[2]; u16 uF[4];
  u32x4 kuC[2][2], kuN[2][2];              // kTw fragments: [slot][ks], current/next
  auto pfAB = [&](size_t rowbN){
    #pragma unroll
    for (int ks=0; ks<3; ks++){
      size_t gg = (rowbN + w*16 + l16)*96 + ks*32 + quad*8;
      kcdF[ks] = *(const u32x4*)(kcd + gg);
      qF[ks]   = *(const u32x4*)(qn + gg);
    }
  };
  auto pfATT = [&](size_t abN){
    #pragma unroll
    for (int ks=0; ks<2; ks++)
      attF[ks] = *(const u32x4*)(attn + abN + (w*16 + l16)*64 + ks*32 + quad*8);
  };
  auto pfU = [&](size_t rowbN){
    #pragma unroll
    for (int r=0;r<4;r++)
      uF[r] = uA[(rowbN + w*16 + quad*4 + r)*192 + e0 + l16];
  };
  auto pfKU = [&](size_t chunkIdx, u32x4 (&dst)[2][2]){
    #pragma unroll
    for (int i=0;i<2;i++){
      int tid = w + 4*i;
      if (tid < 6){
        size_t base = chunkIdx*6144 + (size_t)(tid*16 + l16)*64 + quad*8;
        dst[i][0] = *(const u32x4*)(kTw + base);
        dst[i][1] = *(const u32x4*)(kTw + base + 32);
      }
    }
  };

  // prologue
  pfAB(rowb); pfU(rowb); pfATT(ab);
  pfKU(rowb>>6, kuC);
  f32x4 edC = *(const f32x4*)&edG[rowb + w*16 + quad*4];
  float aexpC = aG[rowb>>6];
  __syncthreads();           // Sbf zeros visible
  f32x4 Sreg[2] = {};

  for (int n=0;n<64;n++){
    const size_t rowbN = rowb + 64;
    const size_t abN = ab + 4096;
    f32x4 edN = {0.f,0.f,0.f,0.f};
    float aexpN = 0.f;
    if (n<63){
      pfKU(rowbN>>6, kuN);
      edN = *(const f32x4*)&edG[rowbN + w*16 + quad*4];
      aexpN = aG[rowbN>>6];
    }
    // phase 1: accA = kcd@S, accQ = q@S
    f32x4 accA = {0.f,0.f,0.f,0.f}, accQ = {0.f,0.f,0.f,0.f};
    #pragma unroll
    for (int ks=0;ks<3;ks++){
      bf16x8 Bf = *(const bf16x8*)&Sbf[l16*104 + ks*32 + quad*8];
      accA = __builtin_amdgcn_mfma_f32_16x16x32_bf16(*(const bf16x8*)&kcdF[ks], Bf, accA,0,0,0);
      accQ = __builtin_amdgcn_mfma_f32_16x16x32_bf16(*(const bf16x8*)&qF[ks],  Bf, accQ,0,0,0);
    }
    #pragma unroll
    for (int r=0;r<4;r++){
      float vn = bf2f(uF[r]) - edC[r]*accA[r];
      vnewT[l16*72 + (w*16+quad*4+r)] = f2bf(vn);
      accQ[r] *= edC[r];
    }
    if (n<63){ pfAB(rowbN); pfU(rowbN); }
    BAR_LGKM();              // sync1: vnewT visible; global prefetches stay in flight
    // phase 2: accQ += attn @ vnew
    #pragma unroll
    for (int ks=0;ks<2;ks++){
      bf16x8 Bv = *(const bf16x8*)&vnewT[l16*72 + ks*32 + quad*8];
      accQ = __builtin_amdgcn_mfma_f32_16x16x32_bf16(*(const bf16x8*)&attF[ks], Bv, accQ,0,0,0);
    }
    #pragma unroll
    for (int r=0;r<4;r++)
      o[(rowb + w*16 + quad*4 + r)*192 + e0 + l16] = f2bf(accQ[r]);
    if (n<63) pfATT(abN);
    // S update: 6 slots over 4 waves, A-operand from kuC registers
    #pragma unroll
    for (int i=0;i<2;i++){
      int tid = w + 4*i;
      if (tid < 6){
        int mt = tid;
        f32x4 acc = (f32x4){0.f,0.f,0.f,0.f};
        #pragma unroll
        for (int ks=0;ks<2;ks++){
          bf16x8 Bv = *(const bf16x8*)&vnewT[l16*72 + ks*32 + quad*8];
          acc = __builtin_amdgcn_mfma_f32_16x16x32_bf16(*(const bf16x8*)&kuC[i][ks], Bv, acc,0,0,0);
        }
        f32x4 ns;
        ns.x = Sreg[i].x*aexpC + acc.x;
        ns.y = Sreg[i].y*aexpC + acc.y;
        ns.z = Sreg[i].z*aexpC + acc.z;
        ns.w = Sreg[i].w*aexpC + acc.w;
        Sreg[i] = ns;
        u32x2 pv;
        pv.x = (u32)f2bf(ns.x) | ((u32)f2bf(ns.y)<<16);
        pv.y = (u32)f2bf(ns.z) | ((u32)f2bf(ns.w)<<16);
        *(u32x2*)&Sbf[l16*104 + mt*16 + quad*4] = pv;
      }
    }
    BAR_LGKM();              // sync2: Sbf visible for next phase 1
    rowb = rowbN; ab = abN;
    edC = edN; aexpC = aexpN;
    kuC[0][0]=kuN[0][0]; kuC[0][1]=kuN[0][1]; kuC[1][0]=kuN[1][0]; kuC[1][1]=kuN[1][1];
  }
}

// ---------------- gated RMSNorm epilogue v2: 8192 blocks, vectorized 8-elem/thread ----------------
__global__ __launch_bounds__(192) void epilogue_kernel(const u16* __restrict__ o,
                                                       const u16* __restrict__ g0, const u16* __restrict__ g1,
                                                       const u16* __restrict__ g2, const u16* __restrict__ g3,
                                                       const void* __restrict__ nw, u16* __restrict__ on,
                                                       const int* __restrict__ flagp){
  const bool f32 = (*flagp != 0);
  const int bl = blockIdx.x;
  const int t = threadIdx.x;
  const int b = bl>>12, l = bl&4095;
  const int h = t/24, d0 = (t - h*24)*8;
  __shared__ float part[192];
  __shared__ float rsS[8];
  u32x4 ov = *(const u32x4*)&o[((size_t)(b*8+h)*4096 + l)*192 + d0];
  float x[8]; unpack8(ov, x);
  float ss = 0.f;
  #pragma unroll
  for (int ch=0;ch<8;ch++) ss += x[ch]*x[ch];
  part[t] = ss;
  __syncthreads();
  if (t < 8){
    float s = 0.f;
    #pragma unroll
    for (int j=0;j<24;j++) s += part[t*24+j];
    rsS[t] = rsqrtf(s/192.f + 1e-5f);
  }
  __syncthreads();
  float rs = rsS[h];
  const u16* gp; int bo;
  if (bl < 5376){ gp = g0; bo = bl; }
  else if (bl < 6656){ gp = g1; bo = bl - 5376; }
  else if (bl < 7680){ gp = g2; bo = bl - 6656; }
  else { gp = g3; bo = bl - 7680; }
  u32x4 gv = *(const u32x4*)&gp[(size_t)bo*1536 + h*192 + d0];
  float gf[8]; unpack8(gv, gf);
  u32x4 nv = ld8bf(nw, d0, f32);
  float nf[8]; unpack8(nv, nf);
  u32x4 pv;
  float r[8];
  #pragma unroll
  for (int ch=0;ch<8;ch++) r[ch] = x[ch]*rs*nf[ch]*gf[ch]*sigx(gf[ch]);
  pv.x = (u32)f2bf(r[0]) | ((u32)f2bf(r[1])<<16);
  pv.y = (u32)f2bf(r[2]) | ((u32)f2bf(r[3])<<16);
  pv.z = (u32)f2bf(r[4]) | ((u32)f2bf(r[5])<<16);
  pv.w = (u32)f2bf(r[6]) | ((u32)f2bf(r[7])<<16);
  *(u32x4*)&on[(size_t)bl*1536 + h*192 + d0] = pv;
}

// ---------------- launch ----------------
extern "C" void kernel_launch(void* const* d_in, const int* in_sizes, int n_in,
                              void* d_out, int out_size, void* d_ws, size_t ws_size,
                              hipStream_t stream){
  (void)in_sizes; (void)n_in; (void)out_size; (void)ws_size;
  const void* u     = d_in[0];
  const void* Wq    = d_in[1];
  const void* Wk    = d_in[2];
  const void* Wv    = d_in[3];
  const void* Wg    = d_in[4];
  const void* Wo    = d_in[5];
  const void* Wgk   = d_in[6];
  const void* Wb    = d_in[7];
  const void* b_b   = d_in[8];
  const void* A_log = d_in[9];
  const void* dt_b  = d_in[10];
  const void* cq    = d_in[11];
  const void* ck    = d_in[12];
  const void* cv    = d_in[13];
  const void* nw    = d_in[14];

  char* w = (char*)d_ws;
  size_t off = 0;
  auto take = [&](size_t bytes)->char*{
    char* p = w + off;
    off += (bytes + 255) & ~(size_t)255;
    return p;
  };
  int* flag = (int*)take(256);
  u16* WqT  = (u16*)take((size_t)768*1024*2);
  u16* WkT  = (u16*)take((size_t)768*1024*2);
  u16* WvT  = (u16*)take((size_t)1536*1024*2);
  u16* WgT  = (u16*)take((size_t)1536*1024*2);
  u16* WoT  = (u16*)take((size_t)1024*1536*2);
  u16* qraw = (u16*)take((size_t)8192*768*2);
  u16* kraw = (u16*)take((size_t)8192*768*2);
  u16* vraw = (u16*)take((size_t)8192*1536*2);
  u16* qn   = (u16*)take((size_t)8192*768*2);
  u16* kn   = (u16*)take((size_t)8192*768*2);   // after chunkprep this region holds kTw (block-local alias)
  u16* vb   = (u16*)take((size_t)8192*1536*2);
  u16* ubf  = (u16*)take((size_t)8192*1024*2);  // bf16 copy of u (A for qkv + glin GEMMs)
  u16* cqb  = (u16*)take(3072*2);               // bf16 conv weights (pre-converted once)
  u16* ckb  = (u16*)take(3072*2);
  u16* cvb  = (u16*)take(6144*2);
  float* gkA   = (float*)take(65536*4);
  float* betaA = (float*)take(65536*4);
  float* edG   = (float*)take(65536*4);
  float* aGA   = (float*)take(1024*4);
  u16* attnA = qraw;
  u16* kcdA  = kraw;
  u16* uuA   = vraw;
  u16* oA    = vb;
  u16* onA   = vraw;
  // glin scratch, 4-way row split (5376/1280/1024/512 rows x 1536 bf16), all dead during the fused kernel:
  u16* glin0 = (u16*)d_out;                       // rows 0..5375
  u16* glin1 = attnA + (size_t)1024*64*64;        // rows 5376..6655 (qraw tail after attn)
  u16* glin2 = WvT;                               // rows 6656..7679 (exact fit)
  u16* glin3 = WkT;                               // rows 7680..8191 (exact fit)

  detect_kernel<<<1,64,0,stream>>>((const u16*)u, flag);
  transpose5<<<8240,256,0,stream>>>(Wq, Wk, Wv, Wg, Wo, u, cq, ck, cv,
                                    WqT, WkT, WvT, WgT, WoT, ubf, cqb, ckb, cvb, flag);
  gemm_qkv<<<1536,256,0,stream>>>(ubf, WqT, WkT, WvT, qraw, kraw, vraw);
  prep_kernel<<<8192,384,0,stream>>>(u, Wgk, Wb, b_b, A_log, dt_b,
                                     qraw, kraw, vraw, cqb, ckb, cvb,
                                     gkA, betaA, qn, kn, vb, flag);
  chunkprep_kernel<<<1024,320,0,stream>>>(qn, kn, vb, betaA, gkA, attnA, kcdA, uuA,
                                          edG, aGA);
  scan_glin_kernel<<<960,256,0,stream>>>(qn, kn /*=kTw*/, kcdA, attnA, uuA, edG, aGA, oA,
                                         ubf, WgT, glin0, glin1, glin2, glin3);
  epilogue_kernel<<<dim3(8192),192,0,stream>>>(oA, glin0, glin1, glin2, glin3, nw, onA, flag);
  gemm_bt<<<512,256,0,stream>>>(onA, WoT, d_out, 8192, 1024, 1536, flag, 0, 1, 1);
}